// Round 7
// baseline (2041.168 us; speedup 1.0000x reference)
//
#include <hip/hip_runtime.h>
#include <math.h>

#define D_MODEL 512
#define N_LAYERS 4
#define D_STATE 16
#define D_CONV 4
#define D_INNER 1024
#define DT_RANK 32
#define BATCH 4
#define SEQ 2048
#define NTOK (BATCH*SEQ)   // 8192
#define NCHUNK 64
#define CL (SEQ/NCHUNK)    // 32
#define LOG2E 1.44269504f

typedef unsigned short ushort_t;
typedef __attribute__((ext_vector_type(8))) short bf8_t;
typedef __attribute__((ext_vector_type(4))) float f4_t;

__device__ __forceinline__ ushort_t f2bf(float f) {
    unsigned u = __float_as_uint(f);
    u += 0x7fffu + ((u >> 16) & 1u);
    return (ushort_t)(u >> 16);
}
__device__ __forceinline__ float bf2f(ushort_t h) {
    return __uint_as_float(((unsigned)h) << 16);
}
__device__ __forceinline__ void gload_lds16(const void* g, void* l) {
    auto* gp = (const __attribute__((address_space(1))) unsigned int*)(unsigned long long)(g);
    auto* lp = (__attribute__((address_space(3))) unsigned int*)(unsigned int)(unsigned long long)(l);
    __builtin_amdgcn_global_load_lds(gp, lp, 16, 0, 0);
}
__device__ __forceinline__ void split4(const float* __restrict__ src,
        ushort_t* __restrict__ dh, ushort_t* __restrict__ dl, int rel)
{
    float4 v = ((const float4*)src)[rel];
    ushort_t h0=f2bf(v.x), h1=f2bf(v.y), h2=f2bf(v.z), h3=f2bf(v.w);
    ((ushort4*)dh)[rel] = make_ushort4(h0,h1,h2,h3);
    ((ushort4*)dl)[rel] = make_ushort4(f2bf(v.x-bf2f(h0)), f2bf(v.y-bf2f(h1)),
                                       f2bf(v.z-bf2f(h2)), f2bf(v.w-bf2f(h3)));
}
// geometric-A fast path: dA[n] = r^(n+1), r = exp2(dv*A2[0]); else 16 exps.
__device__ __forceinline__ void mk_dA(float dv, const float* A2, bool geo, float* dA)
{
    if (geo) {
        float r1 = exp2f(dv * A2[0]);
        float r2 = r1*r1, r4 = r2*r2, r8 = r4*r4;
        dA[0]=r1;  dA[1]=r2;     dA[2]=r2*r1;    dA[3]=r4;
        dA[4]=r4*r1; dA[5]=r4*r2; dA[6]=r4*r2*r1; dA[7]=r8;
        dA[8]=r8*r1; dA[9]=r8*r2; dA[10]=r8*r2*r1; dA[11]=r8*r4;
        dA[12]=r8*r4*r1; dA[13]=r8*r4*r2; dA[14]=r8*r4*r2*r1; dA[15]=r8*r8;
    } else {
#pragma unroll
        for (int n = 0; n < 16; ++n) dA[n] = exp2f(dv * A2[n]);
    }
}

// ===== prep: LN (2048 blks) | split in_w (1024) | out_w (512) | xp_w (64) | dt_w (32) =====
__global__ __launch_bounds__(256) void prep(
    const float* __restrict__ x, const float* __restrict__ nw, const float* __restrict__ nb,
    ushort_t* __restrict__ xnh, ushort_t* __restrict__ xnl,
    const float* __restrict__ inw, ushort_t* __restrict__ wih, ushort_t* __restrict__ wil,
    const float* __restrict__ outw, ushort_t* __restrict__ woh, ushort_t* __restrict__ wol,
    const float* __restrict__ xpw, ushort_t* __restrict__ xph, ushort_t* __restrict__ xpl,
    const float* __restrict__ dtw, ushort_t* __restrict__ dwh, ushort_t* __restrict__ dwl)
{
    int bid = blockIdx.x, tid = threadIdx.x;
    if (bid < 2048) {
        int wave = tid >> 6, lane = tid & 63;
        int row = bid * 4 + wave;
        const float* xr = x + (size_t)row * D_MODEL;
        float v[8];
        float s = 0.f;
#pragma unroll
        for (int i = 0; i < 8; ++i) { v[i] = xr[lane + i*64]; s += v[i]; }
#pragma unroll
        for (int off = 32; off > 0; off >>= 1) s += __shfl_xor(s, off, 64);
        float mu = s * (1.f/512.f);
        float q = 0.f;
#pragma unroll
        for (int i = 0; i < 8; ++i) { float d = v[i]-mu; q += d*d; }
#pragma unroll
        for (int off = 32; off > 0; off >>= 1) q += __shfl_xor(q, off, 64);
        float rstd = rsqrtf(q * (1.f/512.f) + 1e-5f);
#pragma unroll
        for (int i = 0; i < 8; ++i) {
            int e = lane + i*64;
            float vv = (v[i]-mu)*rstd*nw[e] + nb[e];
            ushort_t h = f2bf(vv);
            xnh[(size_t)row*D_MODEL + e] = h;
            xnl[(size_t)row*D_MODEL + e] = f2bf(vv - bf2f(h));
        }
    } else if (bid < 3072) {
        split4(inw, wih, wil, (bid-2048)*256 + tid);          // 262144 f4
    } else if (bid < 3584) {
        split4(outw, woh, wol, (bid-3072)*256 + tid);         // 131072 f4
    } else if (bid < 3648) {
        split4(xpw, xph, xpl, (bid-3584)*256 + tid);          // 16384 f4
    } else {
        split4(dtw, dwh, dwl, (bid-3648)*256 + tid);          // 8192 f4
    }
}

// ------- bf16 split-MFMA NT GEMM (r3-verified) -------
template<int BM, int BN, bool RES>
__global__ __launch_bounds__(256) void gemm_bf16s(
    const ushort_t* __restrict__ Ahi, const ushort_t* __restrict__ Alo, int lda,
    const ushort_t* __restrict__ Bhi, const ushort_t* __restrict__ Blo, int ldb,
    float* __restrict__ C, int ldc, const float* __restrict__ resid, int K)
{
    constexpr int MR = BM/32, NR = BN/32;
    __shared__ __align__(16) char lds[(2*BM + 2*BN)*64];
    char* lAh = lds;
    char* lAl = lds + BM*64;
    char* lBh = lds + 2*BM*64;
    char* lBl = lds + 2*BM*64 + BN*64;
    int tid = threadIdx.x;
    int lane = tid & 63, wave = tid >> 6;
    int row0 = blockIdx.y * BM, col0 = blockIdx.x * BN;
    int wr = wave >> 1, wc = wave & 1;
    f4_t acc[MR][NR];
#pragma unroll
    for (int m=0;m<MR;++m)
#pragma unroll
        for (int n=0;n<NR;++n)
#pragma unroll
            for (int j=0;j<4;++j) acc[m][n][j] = 0.f;

    int srow = tid >> 2;
    int scol = (tid & 3) * 8;
    int koff = (lane >> 4) * 16;
    int fr = lane & 15;

    for (int k0 = 0; k0 < K; k0 += 32) {
        __syncthreads();
        gload_lds16(Ahi + (size_t)(row0 + srow)*lda + k0 + scol, lAh + wave*1024);
        gload_lds16(Alo + (size_t)(row0 + srow)*lda + k0 + scol, lAl + wave*1024);
        if (BM == 128) {
            gload_lds16(Ahi + (size_t)(row0 + 64 + srow)*lda + k0 + scol, lAh + 4096 + wave*1024);
            gload_lds16(Alo + (size_t)(row0 + 64 + srow)*lda + k0 + scol, lAl + 4096 + wave*1024);
        }
        gload_lds16(Bhi + (size_t)(col0 + srow)*ldb + k0 + scol, lBh + wave*1024);
        gload_lds16(Blo + (size_t)(col0 + srow)*ldb + k0 + scol, lBl + wave*1024);
        if (BN == 128) {
            gload_lds16(Bhi + (size_t)(col0 + 64 + srow)*ldb + k0 + scol, lBh + 4096 + wave*1024);
            gload_lds16(Blo + (size_t)(col0 + 64 + srow)*ldb + k0 + scol, lBl + 4096 + wave*1024);
        }
        __syncthreads();
        bf8_t ah[MR], al[MR], bh[NR], bl[NR];
#pragma unroll
        for (int m=0;m<MR;++m) {
            int r = wr*(BM/2) + m*16 + fr;
            ah[m] = *(const bf8_t*)(lAh + r*64 + koff);
            al[m] = *(const bf8_t*)(lAl + r*64 + koff);
        }
#pragma unroll
        for (int n=0;n<NR;++n) {
            int c = wc*(BN/2) + n*16 + fr;
            bh[n] = *(const bf8_t*)(lBh + c*64 + koff);
            bl[n] = *(const bf8_t*)(lBl + c*64 + koff);
        }
#pragma unroll
        for (int m=0;m<MR;++m)
#pragma unroll
            for (int n=0;n<NR;++n) {
                acc[m][n] = __builtin_amdgcn_mfma_f32_16x16x32_bf16(ah[m], bh[n], acc[m][n], 0,0,0);
                acc[m][n] = __builtin_amdgcn_mfma_f32_16x16x32_bf16(ah[m], bl[n], acc[m][n], 0,0,0);
                acc[m][n] = __builtin_amdgcn_mfma_f32_16x16x32_bf16(al[m], bh[n], acc[m][n], 0,0,0);
            }
    }
    int fq = (lane >> 4) * 4;
#pragma unroll
    for (int m=0;m<MR;++m)
#pragma unroll
        for (int n=0;n<NR;++n)
#pragma unroll
            for (int j=0;j<4;++j) {
                int r = row0 + wr*(BM/2) + m*16 + fq + j;
                int c = col0 + wc*(BN/2) + n*16 + fr;
                float v = acc[m][n][j];
                if (RES) v += resid[(size_t)r*ldc + c];
                C[(size_t)r*ldc + c] = v;
            }
}

// ---- x_proj split-bf16 MFMA + fused dt_proj+softplus epilogue ----
// main loop identical to r6-verified xproj_mfma; dt-GEMM epilogue ports r5's
// correctness-proven fragment math (rows extended 32->128).
__global__ __launch_bounds__(256) void xproj_dt(
    const ushort_t* __restrict__ Ahi, const ushort_t* __restrict__ Alo,  // u [8192][1024]
    const ushort_t* __restrict__ Bhi, const ushort_t* __restrict__ Blo,  // xp_w [64][1024]
    const ushort_t* __restrict__ dtwh, const ushort_t* __restrict__ dtwl,// [1024][32]
    const float* __restrict__ dtb,     // [1024]
    float* __restrict__ C,             // xdbl [8192][64], cols 32..63 written
    float* __restrict__ delta)         // [8192][1024]
{
    __shared__ __align__(16) char lds[32768];
    char* lAh = lds;                    // [128][64B]
    char* lAl = lds + 8192;
    char* lBh = lds + 16384;            // [64][64B]
    char* lBl = lds + 20480;
    // phase-2 overlay (phase-1 LDS dead after last k-iter + barrier)
    ushort_t (*dth)[32]  = (ushort_t(*)[32])lds;             // [128][32]
    ushort_t (*dtl)[32]  = (ushort_t(*)[32])(lds + 8192);
    ushort_t (*dwhh)[32] = (ushort_t(*)[32])(lds + 16384);   // [128][32]
    ushort_t (*dwll)[32] = (ushort_t(*)[32])(lds + 24576);

    int tid = threadIdx.x;
    int lane = tid & 63, wave = tid >> 6;
    int row0 = blockIdx.x * 128;
    int wr = wave >> 1, wc = wave & 1;
    f4_t acc[4][2];
#pragma unroll
    for (int m=0;m<4;++m)
#pragma unroll
        for (int n=0;n<2;++n)
#pragma unroll
            for (int j=0;j<4;++j) acc[m][n][j] = 0.f;
    int srow = tid >> 2;
    int scol = (tid & 3) * 8;
    int koff = (lane >> 4) * 16;
    int fr = lane & 15, q = lane >> 4, fq = q * 4;
    for (int k0 = 0; k0 < 1024; k0 += 32) {
        __syncthreads();
        gload_lds16(Ahi + (size_t)(row0 + srow)*D_INNER + k0 + scol, lAh + wave*1024);
        gload_lds16(Alo + (size_t)(row0 + srow)*D_INNER + k0 + scol, lAl + wave*1024);
        gload_lds16(Ahi + (size_t)(row0 + 64 + srow)*D_INNER + k0 + scol, lAh + 4096 + wave*1024);
        gload_lds16(Alo + (size_t)(row0 + 64 + srow)*D_INNER + k0 + scol, lAl + 4096 + wave*1024);
        gload_lds16(Bhi + (size_t)srow*D_INNER + k0 + scol, lBh + wave*1024);
        gload_lds16(Blo + (size_t)srow*D_INNER + k0 + scol, lBl + wave*1024);
        __syncthreads();
        bf8_t ah[4], al[4], bh[2], bl[2];
#pragma unroll
        for (int m=0;m<4;++m) {
            int r = wr*64 + m*16 + fr;
            ah[m] = *(const bf8_t*)(lAh + r*64 + koff);
            al[m] = *(const bf8_t*)(lAl + r*64 + koff);
        }
#pragma unroll
        for (int n=0;n<2;++n) {
            int c = wc*32 + n*16 + fr;
            bh[n] = *(const bf8_t*)(lBh + c*64 + koff);
            bl[n] = *(const bf8_t*)(lBl + c*64 + koff);
        }
#pragma unroll
        for (int m=0;m<4;++m)
#pragma unroll
            for (int n=0;n<2;++n) {
                acc[m][n] = __builtin_amdgcn_mfma_f32_16x16x32_bf16(ah[m], bh[n], acc[m][n], 0,0,0);
                acc[m][n] = __builtin_amdgcn_mfma_f32_16x16x32_bf16(ah[m], bl[n], acc[m][n], 0,0,0);
                acc[m][n] = __builtin_amdgcn_mfma_f32_16x16x32_bf16(al[m], bh[n], acc[m][n], 0,0,0);
            }
    }
    __syncthreads();   // phase-1 LDS reads drained; overlay becomes writable
    // epilogue split: wc==1 -> B|C cols 32..63 to xdbl; wc==0 -> dt cols to LDS split
#pragma unroll
    for (int m=0;m<4;++m)
#pragma unroll
        for (int n=0;n<2;++n)
#pragma unroll
            for (int j=0;j<4;++j) {
                int r = wr*64 + m*16 + fq + j;
                int oc = wc*32 + n*16 + fr;
                float v = acc[m][n][j];
                if (wc == 1) {
                    C[(size_t)(row0 + r)*64 + oc] = v;
                } else {
                    ushort_t hv = f2bf(v);
                    dth[r][oc] = hv;
                    dtl[r][oc] = f2bf(v - bf2f(hv));
                }
            }
    // dt GEMM: delta[128 tok][1024] = softplus(dt @ dtw^T + b), 8 chunks of 128
    for (int ch = 0; ch < 8; ++ch) {
        __syncthreads();
        for (int i = tid; i < 512; i += 256) {
            int o = i >> 2, c8 = (i & 3) * 8;
            *(uint4*)&dwhh[o][c8] = *(const uint4*)&dtwh[(size_t)(ch*128 + o)*DT_RANK + c8];
            *(uint4*)&dwll[o][c8] = *(const uint4*)&dtwl[(size_t)(ch*128 + o)*DT_RANK + c8];
        }
        __syncthreads();
#pragma unroll
        for (int m = 0; m < 4; ++m) {
            bf8_t ah = *(const bf8_t*)&dth[wr*64 + m*16 + fr][q*8];
            bf8_t al = *(const bf8_t*)&dtl[wr*64 + m*16 + fr][q*8];
#pragma unroll
            for (int n = 0; n < 4; ++n) {
                int oc = wc*64 + n*16 + fr;
                bf8_t bh = *(const bf8_t*)&dwhh[oc][q*8];
                bf8_t bl = *(const bf8_t*)&dwll[oc][q*8];
                f4_t dacc;
#pragma unroll
                for (int j=0;j<4;++j) dacc[j] = 0.f;
                dacc = __builtin_amdgcn_mfma_f32_16x16x32_bf16(ah, bh, dacc, 0,0,0);
                dacc = __builtin_amdgcn_mfma_f32_16x16x32_bf16(ah, bl, dacc, 0,0,0);
                dacc = __builtin_amdgcn_mfma_f32_16x16x32_bf16(al, bh, dacc, 0,0,0);
                int og = ch*128 + oc;
                float bb = dtb[og];
#pragma unroll
                for (int j = 0; j < 4; ++j) {
                    int trow = wr*64 + m*16 + fq + j;
                    float sv = dacc[j] + bb;
                    float sp = fmaxf(sv,0.f) + log1pf(__expf(-fabsf(sv)));
                    delta[(size_t)(row0 + trow)*D_INNER + og] = sp;
                }
            }
        }
    }
}

// ---------------- causal depthwise conv (k=4) + SiLU -> bf16 hi/lo ----------------
__global__ __launch_bounds__(256) void conv_silu(const float* __restrict__ xz,
                        const float* __restrict__ cw, const float* __restrict__ cb,
                        ushort_t* __restrict__ uh, ushort_t* __restrict__ ul)
{
    int idx = blockIdx.x * 256 + threadIdx.x;   // (b*SEQ+t)*1024 + d
    int d = idx & (D_INNER-1);
    int t = (idx >> 10) & (SEQ-1);
    float w0 = cw[d*4+0], w1 = cw[d*4+1], w2 = cw[d*4+2], w3 = cw[d*4+3];
    float s = cb[d];
    const float* base = xz + ((size_t)(idx >> 10))*2048 + d;
    if (t >= 3) s = fmaf(w0, base[-3*2048], s);
    if (t >= 2) s = fmaf(w1, base[-2*2048], s);
    if (t >= 1) s = fmaf(w2, base[-1*2048], s);
    s = fmaf(w3, base[0], s);
    float uv = s / (1.f + __expf(-s));
    ushort_t h = f2bf(uv);
    uh[idx] = h;
    ul[idx] = f2bf(uv - bf2f(h));
}

// ======== chunked parallel selective scan (NCHUNK=64, geo fast path) ========
__global__ __launch_bounds__(256) void scan_partial(const float* __restrict__ delta,
                        const ushort_t* __restrict__ uh, const ushort_t* __restrict__ ul,
                        const float* __restrict__ xdbl,
                        const float* __restrict__ A_log,
                        float* __restrict__ P, float* __restrict__ S)
{
    int d = blockIdx.x * 256 + threadIdx.x;
    int c = blockIdx.y;
    int b = blockIdx.z;
    int t0 = c * CL;
    __shared__ float Bsh[CL][16];
    for (int i = threadIdx.x; i < CL*16; i += 256) {
        int tt = i >> 4, n = i & 15;
        Bsh[tt][n] = xdbl[((size_t)(b*SEQ + t0 + tt))*64 + 32 + n];
    }
    __syncthreads();
    float A2[D_STATE];
#pragma unroll
    for (int n = 0; n < D_STATE; ++n)
        A2[n] = -expf(A_log[(size_t)d*D_STATE + n]) * LOG2E;
    bool geo = true;
#pragma unroll
    for (int n = 1; n < D_STATE; ++n)
        geo = geo && (fabsf(A2[n] - (n+1)*A2[0]) <= 1e-4f*fabsf(A2[n]));
    float h[D_STATE];
#pragma unroll
    for (int n = 0; n < D_STATE; ++n) h[n] = 0.f;
    float sdv = 0.f;
    const float* dl = delta + ((size_t)(b*SEQ + t0))*D_INNER + d;
    const ushort_t* uhp = uh + ((size_t)(b*SEQ + t0))*D_INNER + d;
    const ushort_t* ulp = ul + ((size_t)(b*SEQ + t0))*D_INNER + d;
#pragma unroll 4
    for (int t = 0; t < CL; ++t) {
        float dv = dl[(size_t)t*D_INNER];
        float uv = bf2f(uhp[(size_t)t*D_INNER]) + bf2f(ulp[(size_t)t*D_INNER]);
        float du = dv * uv;
        sdv += dv;
        float dA[D_STATE];
        mk_dA(dv, A2, geo, dA);
#pragma unroll
        for (int n = 0; n < D_STATE; ++n)
            h[n] = fmaf(dA[n], h[n], Bsh[t][n] * du);
    }
    size_t base = (((size_t)b*D_INNER + d)*NCHUNK + c)*16;
#pragma unroll
    for (int n = 0; n < D_STATE; ++n) P[base+n] = exp2f(A2[n]*sdv);
#pragma unroll
    for (int n = 0; n < D_STATE; n += 4)
        *(float4*)&S[base+n] = make_float4(h[n],h[n+1],h[n+2],h[n+3]);
}

// in-place: S[c] (local sums) is overwritten with h_start(chunk c)
__global__ __launch_bounds__(256) void scan_boundary(const float* __restrict__ P,
                        float* __restrict__ S)
{
    int b = blockIdx.x >> 2;
    int d = ((blockIdx.x & 3) << 8) + threadIdx.x;
    size_t base = ((size_t)b*D_INNER + d)*NCHUNK*16;
    float h[D_STATE];
#pragma unroll
    for (int n = 0; n < D_STATE; ++n) h[n] = 0.f;
    for (int c = 0; c < NCHUNK; ++c) {
        size_t o = base + (size_t)c*16;
#pragma unroll
        for (int n = 0; n < D_STATE; n += 4) {
            float4 p4 = *(const float4*)&P[o+n];
            float4 s4 = *(const float4*)&S[o+n];
            *(float4*)&S[o+n] = make_float4(h[n],h[n+1],h[n+2],h[n+3]);
            h[n+0] = fmaf(p4.x, h[n+0], s4.x);
            h[n+1] = fmaf(p4.y, h[n+1], s4.y);
            h[n+2] = fmaf(p4.z, h[n+2], s4.z);
            h[n+3] = fmaf(p4.w, h[n+3], s4.w);
        }
    }
}

__global__ __launch_bounds__(256) void scan_final(const float* __restrict__ delta,
                        const ushort_t* __restrict__ uh, const ushort_t* __restrict__ ul,
                        float* __restrict__ xz,
                        const float* __restrict__ xdbl,
                        const float* __restrict__ A_log,
                        const float* __restrict__ Dp,
                        const float* __restrict__ Hs)
{
    int d = blockIdx.x * 256 + threadIdx.x;
    int c = blockIdx.y;
    int b = blockIdx.z;
    int t0 = c * CL;
    __shared__ float Bsh[CL][16];
    __shared__ float Csh[CL][16];
    for (int i = threadIdx.x; i < CL*16; i += 256) {
        int tt = i >> 4, n = i & 15;
        size_t xo = ((size_t)(b*SEQ + t0 + tt))*64;
        Bsh[tt][n] = xdbl[xo + 32 + n];
        Csh[tt][n] = xdbl[xo + 48 + n];
    }
    __syncthreads();
    float A2[D_STATE];
#pragma unroll
    for (int n = 0; n < D_STATE; ++n)
        A2[n] = -expf(A_log[(size_t)d*D_STATE + n]) * LOG2E;
    bool geo = true;
#pragma unroll
    for (int n = 1; n < D_STATE; ++n)
        geo = geo && (fabsf(A2[n] - (n+1)*A2[0]) <= 1e-4f*fabsf(A2[n]));
    float Dd = Dp[d];
    float h[D_STATE];
    size_t hbase = (((size_t)b*D_INNER + d)*NCHUNK + c)*16;
#pragma unroll
    for (int n = 0; n < D_STATE; n += 4) {
        float4 h4 = *(const float4*)&Hs[hbase+n];
        h[n]=h4.x; h[n+1]=h4.y; h[n+2]=h4.z; h[n+3]=h4.w;
    }
    const float* dl = delta + ((size_t)(b*SEQ + t0))*D_INNER + d;
    const ushort_t* uhp = uh + ((size_t)(b*SEQ + t0))*D_INNER + d;
    const ushort_t* ulp = ul + ((size_t)(b*SEQ + t0))*D_INNER + d;
    const float* zl = xz + ((size_t)(b*SEQ + t0))*2048 + 1024 + d;
    ushort_t* yrow = (ushort_t*)(xz + ((size_t)(b*SEQ + t0))*2048);
#pragma unroll 4
    for (int t = 0; t < CL; ++t) {
        float dv = dl[(size_t)t*D_INNER];
        float uv = bf2f(uhp[(size_t)t*D_INNER]) + bf2f(ulp[(size_t)t*D_INNER]);
        float zv = zl[(size_t)t*2048];
        float du = dv * uv;
        float dA[D_STATE];
        mk_dA(dv, A2, geo, dA);
        float y = 0.f;
#pragma unroll
        for (int n = 0; n < D_STATE; ++n) {
            h[n] = fmaf(dA[n], h[n], Bsh[t][n] * du);
            y = fmaf(h[n], Csh[t][n], y);
        }
        y = fmaf(uv, Dd, y);
        float sig = 1.f / (1.f + __expf(-zv));
        float yg = y * (zv * sig);
        ushort_t yh = f2bf(yg);
        yrow[(size_t)t*4096 + d] = yh;
        yrow[(size_t)t*4096 + 1024 + d] = f2bf(yg - bf2f(yh));
    }
}

extern "C" void kernel_launch(void* const* d_in, const int* in_sizes, int n_in,
                              void* d_out, int out_size, void* d_ws, size_t ws_size,
                              hipStream_t stream) {
    const float* x_in   = (const float*)d_in[0];
    const float* norm_w = (const float*)d_in[1];
    const float* norm_b = (const float*)d_in[2];
    const float* in_w   = (const float*)d_in[3];
    const float* conv_w = (const float*)d_in[4];
    const float* conv_b = (const float*)d_in[5];
    const float* xp_w   = (const float*)d_in[6];
    const float* dt_w   = (const float*)d_in[7];
    const float* dt_b   = (const float*)d_in[8];
    const float* A_log  = (const float*)d_in[9];
    const float* Dp     = (const float*)d_in[10];
    const float* out_w  = (const float*)d_in[11];
    float* out = (float*)d_out;

    // workspace (~170 MB, r2-proven size)
    float* ws   = (float*)d_ws;
    float* xz   = ws;                           // 64MB f32 (xi|z); y bf16 hi/lo aliased later
    ushort_t* uhb = (ushort_t*)(xz + (size_t)NTOK*2048);   // 16MB
    ushort_t* ulb = uhb + (size_t)NTOK*D_INNER;            // 16MB
    float* xdbl = (float*)(ulb + (size_t)NTOK*D_INNER);    // 2MB
    float* dlt  = xdbl + (size_t)NTOK*64;                  // 32MB (head aliases xnh/xnl)
    float* Pb   = dlt  + (size_t)NTOK*D_INNER;             // 16.8MB
    float* Sb   = Pb   + (size_t)BATCH*D_INNER*NCHUNK*16;  // 16.8MB (becomes Hs in-place)
    ushort_t* wih = (ushort_t*)(Sb + (size_t)BATCH*D_INNER*NCHUNK*16);
    ushort_t* wil = wih + (size_t)2*D_INNER*D_MODEL;
    ushort_t* woh = wil + (size_t)2*D_INNER*D_MODEL;
    ushort_t* wol = woh + (size_t)D_MODEL*D_INNER;
    ushort_t* xph = wol + (size_t)D_MODEL*D_INNER;
    ushort_t* xpl = xph + (size_t)64*D_INNER;
    ushort_t* dwh = xpl + (size_t)64*D_INNER;
    ushort_t* dwl = dwh + (size_t)D_INNER*DT_RANK;
    ushort_t* xnh = (ushort_t*)dlt;             // alias: consumed before dlt written
    ushort_t* xnl = xnh + (size_t)NTOK*D_MODEL;

    for (int l = 0; l < N_LAYERS; ++l) {
        const float* xcur = (l == 0) ? x_in : out;
        prep<<<3680, 256, 0, stream>>>(
            xcur, norm_w + l*D_MODEL, norm_b + l*D_MODEL, xnh, xnl,
            in_w + (size_t)l*2*D_INNER*D_MODEL, wih, wil,
            out_w + (size_t)l*D_MODEL*D_INNER, woh, wol,
            xp_w + (size_t)l*64*D_INNER, xph, xpl,
            dt_w + (size_t)l*D_INNER*DT_RANK, dwh, dwl);
        // xz = xn @ in_w^T   (M=8192, N=2048, K=512)
        gemm_bf16s<128,128,false><<<dim3(2048/128, NTOK/128), 256, 0, stream>>>(
            xnh, xnl, D_MODEL, wih, wil, D_MODEL, xz, 2048, nullptr, D_MODEL);
        // conv + silu -> u bf16 hi/lo
        conv_silu<<<(NTOK*D_INNER)/256, 256, 0, stream>>>(
            xz, conv_w + (size_t)l*D_INNER*D_CONV, conv_b + (size_t)l*D_INNER, uhb, ulb);
        // xdbl(B|C) + delta, fused (M=8192, N=64, K=1024 then K=32 dt GEMM)
        xproj_dt<<<NTOK/128, 256, 0, stream>>>(
            uhb, ulb, xph, xpl, dwh, dwl, dt_b + (size_t)l*D_INNER, xdbl, dlt);
        // chunked scan
        scan_partial<<<dim3(D_INNER/256, NCHUNK, BATCH), 256, 0, stream>>>(
            dlt, uhb, ulb, xdbl, A_log + (size_t)l*D_INNER*D_STATE, Pb, Sb);
        scan_boundary<<<16, 256, 0, stream>>>(Pb, Sb);
        scan_final<<<dim3(D_INNER/256, NCHUNK, BATCH), 256, 0, stream>>>(
            dlt, uhb, ulb, xz, xdbl, A_log + (size_t)l*D_INNER*D_STATE, Dp + (size_t)l*D_INNER, Sb);
        // out = y @ out_w^T + xcur  (M=8192, N=512, K=1024); y bf16 hi/lo packed in xz rows
        gemm_bf16s<64,128,true><<<dim3(D_MODEL/128, NTOK/64), 256, 0, stream>>>(
            (const ushort_t*)xz, (const ushort_t*)xz + 1024, 4096,
            woh, wol, D_INNER, out, D_MODEL, xcur, D_INNER);
    }
}

// Round 8
// 1675.427 us; speedup vs baseline: 1.2183x; 1.2183x over previous
//
#include <hip/hip_runtime.h>
#include <math.h>

#define D_MODEL 512
#define N_LAYERS 4
#define D_STATE 16
#define D_CONV 4
#define D_INNER 1024
#define DT_RANK 32
#define BATCH 4
#define SEQ 2048
#define NTOK (BATCH*SEQ)   // 8192
#define NCHUNK 64
#define CL (SEQ/NCHUNK)    // 32
#define LOG2E 1.44269504f

typedef unsigned short ushort_t;
typedef __attribute__((ext_vector_type(8))) short bf8_t;
typedef __attribute__((ext_vector_type(4))) float f4_t;

__device__ __forceinline__ ushort_t f2bf(float f) {
    unsigned u = __float_as_uint(f);
    u += 0x7fffu + ((u >> 16) & 1u);
    return (ushort_t)(u >> 16);
}
__device__ __forceinline__ float bf2f(ushort_t h) {
    return __uint_as_float(((unsigned)h) << 16);
}
__device__ __forceinline__ void gload_lds16(const void* g, void* l) {
    auto* gp = (const __attribute__((address_space(1))) unsigned int*)(unsigned long long)(g);
    auto* lp = (__attribute__((address_space(3))) unsigned int*)(unsigned int)(unsigned long long)(l);
    __builtin_amdgcn_global_load_lds(gp, lp, 16, 0, 0);
}
__device__ __forceinline__ void split4(const float* __restrict__ src,
        ushort_t* __restrict__ dh, ushort_t* __restrict__ dl, int rel)
{
    float4 v = ((const float4*)src)[rel];
    ushort_t h0=f2bf(v.x), h1=f2bf(v.y), h2=f2bf(v.z), h3=f2bf(v.w);
    ((ushort4*)dh)[rel] = make_ushort4(h0,h1,h2,h3);
    ((ushort4*)dl)[rel] = make_ushort4(f2bf(v.x-bf2f(h0)), f2bf(v.y-bf2f(h1)),
                                       f2bf(v.z-bf2f(h2)), f2bf(v.w-bf2f(h3)));
}
// geometric-A fast path: dA[n] = r^(n+1), r = exp2(dv*A2[0]); else 16 exps.
__device__ __forceinline__ void mk_dA(float dv, const float* A2, bool geo, float* dA)
{
    if (geo) {
        float r1 = exp2f(dv * A2[0]);
        float r2 = r1*r1, r4 = r2*r2, r8 = r4*r4;
        dA[0]=r1;  dA[1]=r2;     dA[2]=r2*r1;    dA[3]=r4;
        dA[4]=r4*r1; dA[5]=r4*r2; dA[6]=r4*r2*r1; dA[7]=r8;
        dA[8]=r8*r1; dA[9]=r8*r2; dA[10]=r8*r2*r1; dA[11]=r8*r4;
        dA[12]=r8*r4*r1; dA[13]=r8*r4*r2; dA[14]=r8*r4*r2*r1; dA[15]=r8*r8;
    } else {
#pragma unroll
        for (int n = 0; n < 16; ++n) dA[n] = exp2f(dv * A2[n]);
    }
}

// ===== prep: LN (2048 blks) | split in_w (1024) | out_w (512) | xp_w (64) =====
__global__ __launch_bounds__(256) void prep(
    const float* __restrict__ x, const float* __restrict__ nw, const float* __restrict__ nb,
    ushort_t* __restrict__ xnh, ushort_t* __restrict__ xnl,
    const float* __restrict__ inw, ushort_t* __restrict__ wih, ushort_t* __restrict__ wil,
    const float* __restrict__ outw, ushort_t* __restrict__ woh, ushort_t* __restrict__ wol,
    const float* __restrict__ xpw, ushort_t* __restrict__ xph, ushort_t* __restrict__ xpl)
{
    int bid = blockIdx.x, tid = threadIdx.x;
    if (bid < 2048) {
        int wave = tid >> 6, lane = tid & 63;
        int row = bid * 4 + wave;
        const float* xr = x + (size_t)row * D_MODEL;
        float v[8];
        float s = 0.f;
#pragma unroll
        for (int i = 0; i < 8; ++i) { v[i] = xr[lane + i*64]; s += v[i]; }
#pragma unroll
        for (int off = 32; off > 0; off >>= 1) s += __shfl_xor(s, off, 64);
        float mu = s * (1.f/512.f);
        float q = 0.f;
#pragma unroll
        for (int i = 0; i < 8; ++i) { float d = v[i]-mu; q += d*d; }
#pragma unroll
        for (int off = 32; off > 0; off >>= 1) q += __shfl_xor(q, off, 64);
        float rstd = rsqrtf(q * (1.f/512.f) + 1e-5f);
#pragma unroll
        for (int i = 0; i < 8; ++i) {
            int e = lane + i*64;
            float vv = (v[i]-mu)*rstd*nw[e] + nb[e];
            ushort_t h = f2bf(vv);
            xnh[(size_t)row*D_MODEL + e] = h;
            xnl[(size_t)row*D_MODEL + e] = f2bf(vv - bf2f(h));
        }
    } else if (bid < 3072) {
        split4(inw, wih, wil, (bid-2048)*256 + tid);          // 262144 f4
    } else if (bid < 3584) {
        split4(outw, woh, wol, (bid-3072)*256 + tid);         // 131072 f4
    } else {
        split4(xpw, xph, xpl, (bid-3584)*256 + tid);          // 16384 f4
    }
}

// ------- bf16 split-MFMA NT GEMM (r3-verified) -------
template<int BM, int BN, bool RES>
__global__ __launch_bounds__(256) void gemm_bf16s(
    const ushort_t* __restrict__ Ahi, const ushort_t* __restrict__ Alo, int lda,
    const ushort_t* __restrict__ Bhi, const ushort_t* __restrict__ Blo, int ldb,
    float* __restrict__ C, int ldc, const float* __restrict__ resid, int K)
{
    constexpr int MR = BM/32, NR = BN/32;
    __shared__ __align__(16) char lds[(2*BM + 2*BN)*64];
    char* lAh = lds;
    char* lAl = lds + BM*64;
    char* lBh = lds + 2*BM*64;
    char* lBl = lds + 2*BM*64 + BN*64;
    int tid = threadIdx.x;
    int lane = tid & 63, wave = tid >> 6;
    int row0 = blockIdx.y * BM, col0 = blockIdx.x * BN;
    int wr = wave >> 1, wc = wave & 1;
    f4_t acc[MR][NR];
#pragma unroll
    for (int m=0;m<MR;++m)
#pragma unroll
        for (int n=0;n<NR;++n)
#pragma unroll
            for (int j=0;j<4;++j) acc[m][n][j] = 0.f;

    int srow = tid >> 2;
    int scol = (tid & 3) * 8;
    int koff = (lane >> 4) * 16;
    int fr = lane & 15;

    for (int k0 = 0; k0 < K; k0 += 32) {
        __syncthreads();
        gload_lds16(Ahi + (size_t)(row0 + srow)*lda + k0 + scol, lAh + wave*1024);
        gload_lds16(Alo + (size_t)(row0 + srow)*lda + k0 + scol, lAl + wave*1024);
        if (BM == 128) {
            gload_lds16(Ahi + (size_t)(row0 + 64 + srow)*lda + k0 + scol, lAh + 4096 + wave*1024);
            gload_lds16(Alo + (size_t)(row0 + 64 + srow)*lda + k0 + scol, lAl + 4096 + wave*1024);
        }
        gload_lds16(Bhi + (size_t)(col0 + srow)*ldb + k0 + scol, lBh + wave*1024);
        gload_lds16(Blo + (size_t)(col0 + srow)*ldb + k0 + scol, lBl + wave*1024);
        if (BN == 128) {
            gload_lds16(Bhi + (size_t)(col0 + 64 + srow)*ldb + k0 + scol, lBh + 4096 + wave*1024);
            gload_lds16(Blo + (size_t)(col0 + 64 + srow)*ldb + k0 + scol, lBl + 4096 + wave*1024);
        }
        __syncthreads();
        bf8_t ah[MR], al[MR], bh[NR], bl[NR];
#pragma unroll
        for (int m=0;m<MR;++m) {
            int r = wr*(BM/2) + m*16 + fr;
            ah[m] = *(const bf8_t*)(lAh + r*64 + koff);
            al[m] = *(const bf8_t*)(lAl + r*64 + koff);
        }
#pragma unroll
        for (int n=0;n<NR;++n) {
            int c = wc*(BN/2) + n*16 + fr;
            bh[n] = *(const bf8_t*)(lBh + c*64 + koff);
            bl[n] = *(const bf8_t*)(lBl + c*64 + koff);
        }
#pragma unroll
        for (int m=0;m<MR;++m)
#pragma unroll
            for (int n=0;n<NR;++n) {
                acc[m][n] = __builtin_amdgcn_mfma_f32_16x16x32_bf16(ah[m], bh[n], acc[m][n], 0,0,0);
                acc[m][n] = __builtin_amdgcn_mfma_f32_16x16x32_bf16(ah[m], bl[n], acc[m][n], 0,0,0);
                acc[m][n] = __builtin_amdgcn_mfma_f32_16x16x32_bf16(al[m], bh[n], acc[m][n], 0,0,0);
            }
    }
    int fq = (lane >> 4) * 4;
#pragma unroll
    for (int m=0;m<MR;++m)
#pragma unroll
        for (int n=0;n<NR;++n)
#pragma unroll
            for (int j=0;j<4;++j) {
                int r = row0 + wr*(BM/2) + m*16 + fq + j;
                int c = col0 + wc*(BN/2) + n*16 + fr;
                float v = acc[m][n][j];
                if (RES) v += resid[(size_t)r*ldc + c];
                C[(size_t)r*ldc + c] = v;
            }
}

// ---- x_proj split-bf16 MFMA, BM=64 + K-split x4, atomicAdd epilogue ----
// grid (4 ksplit, 128 rowblocks) = 512 blocks. xdbl must be zeroed first.
__global__ __launch_bounds__(256) void xproj_ks(
    const ushort_t* __restrict__ Ahi, const ushort_t* __restrict__ Alo,  // u [8192][1024]
    const ushort_t* __restrict__ Bhi, const ushort_t* __restrict__ Blo,  // xp_w [64][1024]
    float* __restrict__ C)                                                // xdbl [8192][64]
{
    __shared__ __align__(16) char lds[16384];
    char* lAh = lds;            // [64][64B]
    char* lAl = lds + 4096;
    char* lBh = lds + 8192;     // [64][64B]
    char* lBl = lds + 12288;
    int tid = threadIdx.x;
    int lane = tid & 63, wave = tid >> 6;
    int row0 = blockIdx.y * 64;
    int kbeg = blockIdx.x * 256;
    int wr = wave >> 1, wc = wave & 1;
    f4_t acc[2][2];
#pragma unroll
    for (int m=0;m<2;++m)
#pragma unroll
        for (int n=0;n<2;++n)
#pragma unroll
            for (int j=0;j<4;++j) acc[m][n][j] = 0.f;
    int srow = tid >> 2;
    int scol = (tid & 3) * 8;
    int koff = (lane >> 4) * 16;
    int fr = lane & 15;
    for (int k0 = kbeg; k0 < kbeg + 256; k0 += 32) {
        __syncthreads();
        gload_lds16(Ahi + (size_t)(row0 + srow)*D_INNER + k0 + scol, lAh + wave*1024);
        gload_lds16(Alo + (size_t)(row0 + srow)*D_INNER + k0 + scol, lAl + wave*1024);
        gload_lds16(Bhi + (size_t)srow*D_INNER + k0 + scol, lBh + wave*1024);
        gload_lds16(Blo + (size_t)srow*D_INNER + k0 + scol, lBl + wave*1024);
        __syncthreads();
        bf8_t ah[2], al[2], bh[2], bl[2];
#pragma unroll
        for (int m=0;m<2;++m) {
            int r = wr*32 + m*16 + fr;
            ah[m] = *(const bf8_t*)(lAh + r*64 + koff);
            al[m] = *(const bf8_t*)(lAl + r*64 + koff);
        }
#pragma unroll
        for (int n=0;n<2;++n) {
            int c = wc*32 + n*16 + fr;
            bh[n] = *(const bf8_t*)(lBh + c*64 + koff);
            bl[n] = *(const bf8_t*)(lBl + c*64 + koff);
        }
#pragma unroll
        for (int m=0;m<2;++m)
#pragma unroll
            for (int n=0;n<2;++n) {
                acc[m][n] = __builtin_amdgcn_mfma_f32_16x16x32_bf16(ah[m], bh[n], acc[m][n], 0,0,0);
                acc[m][n] = __builtin_amdgcn_mfma_f32_16x16x32_bf16(ah[m], bl[n], acc[m][n], 0,0,0);
                acc[m][n] = __builtin_amdgcn_mfma_f32_16x16x32_bf16(al[m], bh[n], acc[m][n], 0,0,0);
            }
    }
    int fq = (lane >> 4) * 4;
#pragma unroll
    for (int m=0;m<2;++m)
#pragma unroll
        for (int n=0;n<2;++n)
#pragma unroll
            for (int j=0;j<4;++j) {
                int r = row0 + wr*32 + m*16 + fq + j;
                int c = wc*32 + n*16 + fr;
                atomicAdd(&C[(size_t)r*64 + c], acc[m][n][j]);
            }
}

// ---------------- causal depthwise conv (k=4) + SiLU -> bf16 hi/lo ----------------
__global__ __launch_bounds__(256) void conv_silu(const float* __restrict__ xz,
                        const float* __restrict__ cw, const float* __restrict__ cb,
                        ushort_t* __restrict__ uh, ushort_t* __restrict__ ul)
{
    int idx = blockIdx.x * 256 + threadIdx.x;   // (b*SEQ+t)*1024 + d
    int d = idx & (D_INNER-1);
    int t = (idx >> 10) & (SEQ-1);
    float w0 = cw[d*4+0], w1 = cw[d*4+1], w2 = cw[d*4+2], w3 = cw[d*4+3];
    float s = cb[d];
    const float* base = xz + ((size_t)(idx >> 10))*2048 + d;
    if (t >= 3) s = fmaf(w0, base[-3*2048], s);
    if (t >= 2) s = fmaf(w1, base[-2*2048], s);
    if (t >= 1) s = fmaf(w2, base[-1*2048], s);
    s = fmaf(w3, base[0], s);
    float uv = s / (1.f + __expf(-s));
    ushort_t h = f2bf(uv);
    uh[idx] = h;
    ul[idx] = f2bf(uv - bf2f(h));
}

// ---------------- dt_proj (K=32) + bias + softplus, 8 tokens/block (r3-verified) -------
__global__ __launch_bounds__(256) void dt_softplus(const float* __restrict__ xdbl,
                        const float* __restrict__ dtw, const float* __restrict__ dtb,
                        float* __restrict__ delta)
{
    __shared__ float xr[8][32];
    int t0 = blockIdx.x * 8;
    int tid = threadIdx.x;
    {
        int tt = tid >> 5, r = tid & 31;
        xr[tt][r] = xdbl[(size_t)(t0+tt)*64 + r];
    }
    __syncthreads();
#pragma unroll
    for (int jj = 0; jj < 4; ++jj) {
        int j = (jj<<8) + tid;
        const float* w = dtw + (size_t)j*DT_RANK;
        float bj = dtb[j];
        float acc[8];
#pragma unroll
        for (int tt=0;tt<8;++tt) acc[tt]=bj;
#pragma unroll
        for (int r=0;r<DT_RANK;r+=4){
            float4 w4 = *(const float4*)(w+r);
#pragma unroll
            for (int tt=0;tt<8;++tt){
                acc[tt] = fmaf(xr[tt][r+0], w4.x, acc[tt]);
                acc[tt] = fmaf(xr[tt][r+1], w4.y, acc[tt]);
                acc[tt] = fmaf(xr[tt][r+2], w4.z, acc[tt]);
                acc[tt] = fmaf(xr[tt][r+3], w4.w, acc[tt]);
            }
        }
#pragma unroll
        for (int tt=0;tt<8;++tt){
            float s = acc[tt];
            float sp = fmaxf(s,0.f) + log1pf(__expf(-fabsf(s)));
            delta[(size_t)(t0+tt)*D_INNER + j] = sp;
        }
    }
}

// ======== chunked parallel selective scan (r7-verified: NCHUNK=64, geo) ========
__global__ __launch_bounds__(256) void scan_partial(const float* __restrict__ delta,
                        const ushort_t* __restrict__ uh, const ushort_t* __restrict__ ul,
                        const float* __restrict__ xdbl,
                        const float* __restrict__ A_log,
                        float* __restrict__ P, float* __restrict__ S)
{
    int d = blockIdx.x * 256 + threadIdx.x;
    int c = blockIdx.y;
    int b = blockIdx.z;
    int t0 = c * CL;
    __shared__ float Bsh[CL][16];
    for (int i = threadIdx.x; i < CL*16; i += 256) {
        int tt = i >> 4, n = i & 15;
        Bsh[tt][n] = xdbl[((size_t)(b*SEQ + t0 + tt))*64 + 32 + n];
    }
    __syncthreads();
    float A2[D_STATE];
#pragma unroll
    for (int n = 0; n < D_STATE; ++n)
        A2[n] = -expf(A_log[(size_t)d*D_STATE + n]) * LOG2E;
    bool geo = true;
#pragma unroll
    for (int n = 1; n < D_STATE; ++n)
        geo = geo && (fabsf(A2[n] - (n+1)*A2[0]) <= 1e-4f*fabsf(A2[n]));
    float h[D_STATE];
#pragma unroll
    for (int n = 0; n < D_STATE; ++n) h[n] = 0.f;
    float sdv = 0.f;
    const float* dl = delta + ((size_t)(b*SEQ + t0))*D_INNER + d;
    const ushort_t* uhp = uh + ((size_t)(b*SEQ + t0))*D_INNER + d;
    const ushort_t* ulp = ul + ((size_t)(b*SEQ + t0))*D_INNER + d;
#pragma unroll 4
    for (int t = 0; t < CL; ++t) {
        float dv = dl[(size_t)t*D_INNER];
        float uv = bf2f(uhp[(size_t)t*D_INNER]) + bf2f(ulp[(size_t)t*D_INNER]);
        float du = dv * uv;
        sdv += dv;
        float dA[D_STATE];
        mk_dA(dv, A2, geo, dA);
#pragma unroll
        for (int n = 0; n < D_STATE; ++n)
            h[n] = fmaf(dA[n], h[n], Bsh[t][n] * du);
    }
    size_t base = (((size_t)b*D_INNER + d)*NCHUNK + c)*16;
#pragma unroll
    for (int n = 0; n < D_STATE; ++n) P[base+n] = exp2f(A2[n]*sdv);
#pragma unroll
    for (int n = 0; n < D_STATE; n += 4)
        *(float4*)&S[base+n] = make_float4(h[n],h[n+1],h[n+2],h[n+3]);
}

// in-place: S[c] (local sums) is overwritten with h_start(chunk c)
__global__ __launch_bounds__(256) void scan_boundary(const float* __restrict__ P,
                        float* __restrict__ S)
{
    int b = blockIdx.x >> 2;
    int d = ((blockIdx.x & 3) << 8) + threadIdx.x;
    size_t base = ((size_t)b*D_INNER + d)*NCHUNK*16;
    float h[D_STATE];
#pragma unroll
    for (int n = 0; n < D_STATE; ++n) h[n] = 0.f;
    for (int c = 0; c < NCHUNK; ++c) {
        size_t o = base + (size_t)c*16;
#pragma unroll
        for (int n = 0; n < D_STATE; n += 4) {
            float4 p4 = *(const float4*)&P[o+n];
            float4 s4 = *(const float4*)&S[o+n];
            *(float4*)&S[o+n] = make_float4(h[n],h[n+1],h[n+2],h[n+3]);
            h[n+0] = fmaf(p4.x, h[n+0], s4.x);
            h[n+1] = fmaf(p4.y, h[n+1], s4.y);
            h[n+2] = fmaf(p4.z, h[n+2], s4.z);
            h[n+3] = fmaf(p4.w, h[n+3], s4.w);
        }
    }
}

__global__ __launch_bounds__(256) void scan_final(const float* __restrict__ delta,
                        const ushort_t* __restrict__ uh, const ushort_t* __restrict__ ul,
                        float* __restrict__ xz,
                        const float* __restrict__ xdbl,
                        const float* __restrict__ A_log,
                        const float* __restrict__ Dp,
                        const float* __restrict__ Hs)
{
    int d = blockIdx.x * 256 + threadIdx.x;
    int c = blockIdx.y;
    int b = blockIdx.z;
    int t0 = c * CL;
    __shared__ float Bsh[CL][16];
    __shared__ float Csh[CL][16];
    for (int i = threadIdx.x; i < CL*16; i += 256) {
        int tt = i >> 4, n = i & 15;
        size_t xo = ((size_t)(b*SEQ + t0 + tt))*64;
        Bsh[tt][n] = xdbl[xo + 32 + n];
        Csh[tt][n] = xdbl[xo + 48 + n];
    }
    __syncthreads();
    float A2[D_STATE];
#pragma unroll
    for (int n = 0; n < D_STATE; ++n)
        A2[n] = -expf(A_log[(size_t)d*D_STATE + n]) * LOG2E;
    bool geo = true;
#pragma unroll
    for (int n = 1; n < D_STATE; ++n)
        geo = geo && (fabsf(A2[n] - (n+1)*A2[0]) <= 1e-4f*fabsf(A2[n]));
    float Dd = Dp[d];
    float h[D_STATE];
    size_t hbase = (((size_t)b*D_INNER + d)*NCHUNK + c)*16;
#pragma unroll
    for (int n = 0; n < D_STATE; n += 4) {
        float4 h4 = *(const float4*)&Hs[hbase+n];
        h[n]=h4.x; h[n+1]=h4.y; h[n+2]=h4.z; h[n+3]=h4.w;
    }
    const float* dl = delta + ((size_t)(b*SEQ + t0))*D_INNER + d;
    const ushort_t* uhp = uh + ((size_t)(b*SEQ + t0))*D_INNER + d;
    const ushort_t* ulp = ul + ((size_t)(b*SEQ + t0))*D_INNER + d;
    const float* zl = xz + ((size_t)(b*SEQ + t0))*2048 + 1024 + d;
    ushort_t* yrow = (ushort_t*)(xz + ((size_t)(b*SEQ + t0))*2048);
#pragma unroll 4
    for (int t = 0; t < CL; ++t) {
        float dv = dl[(size_t)t*D_INNER];
        float uv = bf2f(uhp[(size_t)t*D_INNER]) + bf2f(ulp[(size_t)t*D_INNER]);
        float zv = zl[(size_t)t*2048];
        float du = dv * uv;
        float dA[D_STATE];
        mk_dA(dv, A2, geo, dA);
        float y = 0.f;
#pragma unroll
        for (int n = 0; n < D_STATE; ++n) {
            h[n] = fmaf(dA[n], h[n], Bsh[t][n] * du);
            y = fmaf(h[n], Csh[t][n], y);
        }
        y = fmaf(uv, Dd, y);
        float sig = 1.f / (1.f + __expf(-zv));
        float yg = y * (zv * sig);
        ushort_t yh = f2bf(yg);
        yrow[(size_t)t*4096 + d] = yh;
        yrow[(size_t)t*4096 + 1024 + d] = f2bf(yg - bf2f(yh));
    }
}

extern "C" void kernel_launch(void* const* d_in, const int* in_sizes, int n_in,
                              void* d_out, int out_size, void* d_ws, size_t ws_size,
                              hipStream_t stream) {
    const float* x_in   = (const float*)d_in[0];
    const float* norm_w = (const float*)d_in[1];
    const float* norm_b = (const float*)d_in[2];
    const float* in_w   = (const float*)d_in[3];
    const float* conv_w = (const float*)d_in[4];
    const float* conv_b = (const float*)d_in[5];
    const float* xp_w   = (const float*)d_in[6];
    const float* dt_w   = (const float*)d_in[7];
    const float* dt_b   = (const float*)d_in[8];
    const float* A_log  = (const float*)d_in[9];
    const float* Dp     = (const float*)d_in[10];
    const float* out_w  = (const float*)d_in[11];
    float* out = (float*)d_out;

    // workspace (~170 MB, r2-proven size)
    float* ws   = (float*)d_ws;
    float* xz   = ws;                           // 64MB f32 (xi|z); y bf16 hi/lo aliased later
    ushort_t* uhb = (ushort_t*)(xz + (size_t)NTOK*2048);   // 16MB
    ushort_t* ulb = uhb + (size_t)NTOK*D_INNER;            // 16MB
    float* xdbl = (float*)(ulb + (size_t)NTOK*D_INNER);    // 2MB
    float* dlt  = xdbl + (size_t)NTOK*64;                  // 32MB (head aliases xnh/xnl)
    float* Pb   = dlt  + (size_t)NTOK*D_INNER;             // 16.8MB
    float* Sb   = Pb   + (size_t)BATCH*D_INNER*NCHUNK*16;  // 16.8MB (becomes Hs in-place)
    ushort_t* wih = (ushort_t*)(Sb + (size_t)BATCH*D_INNER*NCHUNK*16);
    ushort_t* wil = wih + (size_t)2*D_INNER*D_MODEL;
    ushort_t* woh = wil + (size_t)2*D_INNER*D_MODEL;
    ushort_t* wol = woh + (size_t)D_MODEL*D_INNER;
    ushort_t* xph = wol + (size_t)D_MODEL*D_INNER;
    ushort_t* xpl = xph + (size_t)64*D_INNER;
    ushort_t* xnh = (ushort_t*)dlt;             // alias: consumed before dlt written
    ushort_t* xnl = xnh + (size_t)NTOK*D_MODEL;

    for (int l = 0; l < N_LAYERS; ++l) {
        const float* xcur = (l == 0) ? x_in : out;
        prep<<<3648, 256, 0, stream>>>(
            xcur, norm_w + l*D_MODEL, norm_b + l*D_MODEL, xnh, xnl,
            in_w + (size_t)l*2*D_INNER*D_MODEL, wih, wil,
            out_w + (size_t)l*D_MODEL*D_INNER, woh, wol,
            xp_w + (size_t)l*64*D_INNER, xph, xpl);
        // xz = xn @ in_w^T   (M=8192, N=2048, K=512)
        gemm_bf16s<128,128,false><<<dim3(2048/128, NTOK/128), 256, 0, stream>>>(
            xnh, xnl, D_MODEL, wih, wil, D_MODEL, xz, 2048, nullptr, D_MODEL);
        // conv + silu -> u bf16 hi/lo
        conv_silu<<<(NTOK*D_INNER)/256, 256, 0, stream>>>(
            xz, conv_w + (size_t)l*D_INNER*D_CONV, conv_b + (size_t)l*D_INNER, uhb, ulb);
        // xdbl = u @ xp_w^T  (M=8192, N=64, K=1024), K-split x4 + atomicAdd
        hipMemsetAsync(xdbl, 0, (size_t)NTOK*64*sizeof(float), stream);
        xproj_ks<<<dim3(4, NTOK/64), 256, 0, stream>>>(uhb, ulb, xph, xpl, xdbl);
        // delta = softplus(dt @ dtw^T + b)
        dt_softplus<<<NTOK/8, 256, 0, stream>>>(
            xdbl, dt_w + (size_t)l*D_INNER*DT_RANK, dt_b + (size_t)l*D_INNER, dlt);
        // chunked scan
        scan_partial<<<dim3(D_INNER/256, NCHUNK, BATCH), 256, 0, stream>>>(
            dlt, uhb, ulb, xdbl, A_log + (size_t)l*D_INNER*D_STATE, Pb, Sb);
        scan_boundary<<<16, 256, 0, stream>>>(Pb, Sb);
        scan_final<<<dim3(D_INNER/256, NCHUNK, BATCH), 256, 0, stream>>>(
            dlt, uhb, ulb, xz, xdbl, A_log + (size_t)l*D_INNER*D_STATE, Dp + (size_t)l*D_INNER, Sb);
        // out = y @ out_w^T + xcur  (M=8192, N=512, K=1024); y bf16 hi/lo packed in xz rows
        gemm_bf16s<64,128,true><<<dim3(D_MODEL/128, NTOK/64), 256, 0, stream>>>(
            (const ushort_t*)xz, (const ushort_t*)xz + 1024, 4096,
            woh, wol, D_INNER, out, D_MODEL, xcur, D_INNER);
    }
}

// Round 9
// 1253.951 us; speedup vs baseline: 1.6278x; 1.3361x over previous
//
#include <hip/hip_runtime.h>
#include <math.h>

#define D_MODEL 512
#define N_LAYERS 4
#define D_STATE 16
#define D_CONV 4
#define D_INNER 1024
#define DT_RANK 32
#define BATCH 4
#define SEQ 2048
#define NTOK (BATCH*SEQ)   // 8192
#define NCHUNK 64
#define CL (SEQ/NCHUNK)    // 32
#define LOG2E 1.44269504f

typedef unsigned short ushort_t;
typedef __attribute__((ext_vector_type(8))) short bf8_t;
typedef __attribute__((ext_vector_type(4))) float f4_t;

__device__ __forceinline__ ushort_t f2bf(float f) {
    unsigned u = __float_as_uint(f);
    u += 0x7fffu + ((u >> 16) & 1u);
    return (ushort_t)(u >> 16);
}
__device__ __forceinline__ float bf2f(ushort_t h) {
    return __uint_as_float(((unsigned)h) << 16);
}
__device__ __forceinline__ void gload_lds16(const void* g, void* l) {
    auto* gp = (const __attribute__((address_space(1))) unsigned int*)(unsigned long long)(g);
    auto* lp = (__attribute__((address_space(3))) unsigned int*)(unsigned int)(unsigned long long)(l);
    __builtin_amdgcn_global_load_lds(gp, lp, 16, 0, 0);
}
__device__ __forceinline__ void split4(const float* __restrict__ src,
        ushort_t* __restrict__ dh, ushort_t* __restrict__ dl, int rel)
{
    float4 v = ((const float4*)src)[rel];
    ushort_t h0=f2bf(v.x), h1=f2bf(v.y), h2=f2bf(v.z), h3=f2bf(v.w);
    ((ushort4*)dh)[rel] = make_ushort4(h0,h1,h2,h3);
    ((ushort4*)dl)[rel] = make_ushort4(f2bf(v.x-bf2f(h0)), f2bf(v.y-bf2f(h1)),
                                       f2bf(v.z-bf2f(h2)), f2bf(v.w-bf2f(h3)));
}
// geometric-A fast path: dA[n] = r^(n+1), r = exp2(dv*A2[0]); else 16 exps.
__device__ __forceinline__ void mk_dA(float dv, const float* A2, bool geo, float* dA)
{
    if (geo) {
        float r1 = exp2f(dv * A2[0]);
        float r2 = r1*r1, r4 = r2*r2, r8 = r4*r4;
        dA[0]=r1;  dA[1]=r2;     dA[2]=r2*r1;    dA[3]=r4;
        dA[4]=r4*r1; dA[5]=r4*r2; dA[6]=r4*r2*r1; dA[7]=r8;
        dA[8]=r8*r1; dA[9]=r8*r2; dA[10]=r8*r2*r1; dA[11]=r8*r4;
        dA[12]=r8*r4*r1; dA[13]=r8*r4*r2; dA[14]=r8*r4*r2*r1; dA[15]=r8*r8;
    } else {
#pragma unroll
        for (int n = 0; n < 16; ++n) dA[n] = exp2f(dv * A2[n]);
    }
}

// ===== prep: LN (2048 blks) | split in_w (1024) | out_w (512) | xp_w (64) =====
__global__ __launch_bounds__(256) void prep(
    const float* __restrict__ x, const float* __restrict__ nw, const float* __restrict__ nb,
    ushort_t* __restrict__ xnh, ushort_t* __restrict__ xnl,
    const float* __restrict__ inw, ushort_t* __restrict__ wih, ushort_t* __restrict__ wil,
    const float* __restrict__ outw, ushort_t* __restrict__ woh, ushort_t* __restrict__ wol,
    const float* __restrict__ xpw, ushort_t* __restrict__ xph, ushort_t* __restrict__ xpl)
{
    int bid = blockIdx.x, tid = threadIdx.x;
    if (bid < 2048) {
        int wave = tid >> 6, lane = tid & 63;
        int row = bid * 4 + wave;
        const float* xr = x + (size_t)row * D_MODEL;
        float v[8];
        float s = 0.f;
#pragma unroll
        for (int i = 0; i < 8; ++i) { v[i] = xr[lane + i*64]; s += v[i]; }
#pragma unroll
        for (int off = 32; off > 0; off >>= 1) s += __shfl_xor(s, off, 64);
        float mu = s * (1.f/512.f);
        float q = 0.f;
#pragma unroll
        for (int i = 0; i < 8; ++i) { float d = v[i]-mu; q += d*d; }
#pragma unroll
        for (int off = 32; off > 0; off >>= 1) q += __shfl_xor(q, off, 64);
        float rstd = rsqrtf(q * (1.f/512.f) + 1e-5f);
#pragma unroll
        for (int i = 0; i < 8; ++i) {
            int e = lane + i*64;
            float vv = (v[i]-mu)*rstd*nw[e] + nb[e];
            ushort_t h = f2bf(vv);
            xnh[(size_t)row*D_MODEL + e] = h;
            xnl[(size_t)row*D_MODEL + e] = f2bf(vv - bf2f(h));
        }
    } else if (bid < 3072) {
        split4(inw, wih, wil, (bid-2048)*256 + tid);          // 262144 f4
    } else if (bid < 3584) {
        split4(outw, woh, wol, (bid-3072)*256 + tid);         // 131072 f4
    } else {
        split4(xpw, xph, xpl, (bid-3584)*256 + tid);          // 16384 f4
    }
}

// ------- bf16 split-MFMA NT GEMM (r3-verified) -------
template<int BM, int BN, bool RES>
__global__ __launch_bounds__(256) void gemm_bf16s(
    const ushort_t* __restrict__ Ahi, const ushort_t* __restrict__ Alo, int lda,
    const ushort_t* __restrict__ Bhi, const ushort_t* __restrict__ Blo, int ldb,
    float* __restrict__ C, int ldc, const float* __restrict__ resid, int K)
{
    constexpr int MR = BM/32, NR = BN/32;
    __shared__ __align__(16) char lds[(2*BM + 2*BN)*64];
    char* lAh = lds;
    char* lAl = lds + BM*64;
    char* lBh = lds + 2*BM*64;
    char* lBl = lds + 2*BM*64 + BN*64;
    int tid = threadIdx.x;
    int lane = tid & 63, wave = tid >> 6;
    int row0 = blockIdx.y * BM, col0 = blockIdx.x * BN;
    int wr = wave >> 1, wc = wave & 1;
    f4_t acc[MR][NR];
#pragma unroll
    for (int m=0;m<MR;++m)
#pragma unroll
        for (int n=0;n<NR;++n)
#pragma unroll
            for (int j=0;j<4;++j) acc[m][n][j] = 0.f;

    int srow = tid >> 2;
    int scol = (tid & 3) * 8;
    int koff = (lane >> 4) * 16;
    int fr = lane & 15;

    for (int k0 = 0; k0 < K; k0 += 32) {
        __syncthreads();
        gload_lds16(Ahi + (size_t)(row0 + srow)*lda + k0 + scol, lAh + wave*1024);
        gload_lds16(Alo + (size_t)(row0 + srow)*lda + k0 + scol, lAl + wave*1024);
        if (BM == 128) {
            gload_lds16(Ahi + (size_t)(row0 + 64 + srow)*lda + k0 + scol, lAh + 4096 + wave*1024);
            gload_lds16(Alo + (size_t)(row0 + 64 + srow)*lda + k0 + scol, lAl + 4096 + wave*1024);
        }
        gload_lds16(Bhi + (size_t)(col0 + srow)*ldb + k0 + scol, lBh + wave*1024);
        gload_lds16(Blo + (size_t)(col0 + srow)*ldb + k0 + scol, lBl + wave*1024);
        if (BN == 128) {
            gload_lds16(Bhi + (size_t)(col0 + 64 + srow)*ldb + k0 + scol, lBh + 4096 + wave*1024);
            gload_lds16(Blo + (size_t)(col0 + 64 + srow)*ldb + k0 + scol, lBl + 4096 + wave*1024);
        }
        __syncthreads();
        bf8_t ah[MR], al[MR], bh[NR], bl[NR];
#pragma unroll
        for (int m=0;m<MR;++m) {
            int r = wr*(BM/2) + m*16 + fr;
            ah[m] = *(const bf8_t*)(lAh + r*64 + koff);
            al[m] = *(const bf8_t*)(lAl + r*64 + koff);
        }
#pragma unroll
        for (int n=0;n<NR;++n) {
            int c = wc*(BN/2) + n*16 + fr;
            bh[n] = *(const bf8_t*)(lBh + c*64 + koff);
            bl[n] = *(const bf8_t*)(lBl + c*64 + koff);
        }
#pragma unroll
        for (int m=0;m<MR;++m)
#pragma unroll
            for (int n=0;n<NR;++n) {
                acc[m][n] = __builtin_amdgcn_mfma_f32_16x16x32_bf16(ah[m], bh[n], acc[m][n], 0,0,0);
                acc[m][n] = __builtin_amdgcn_mfma_f32_16x16x32_bf16(ah[m], bl[n], acc[m][n], 0,0,0);
                acc[m][n] = __builtin_amdgcn_mfma_f32_16x16x32_bf16(al[m], bh[n], acc[m][n], 0,0,0);
            }
    }
    int fq = (lane >> 4) * 4;
#pragma unroll
    for (int m=0;m<MR;++m)
#pragma unroll
        for (int n=0;n<NR;++n)
#pragma unroll
            for (int j=0;j<4;++j) {
                int r = row0 + wr*(BM/2) + m*16 + fq + j;
                int c = col0 + wc*(BN/2) + n*16 + fr;
                float v = acc[m][n][j];
                if (RES) v += resid[(size_t)r*ldc + c];
                C[(size_t)r*ldc + c] = v;
            }
}

// ---- x_proj split-bf16 MFMA, BM=64 + K-split x4, atomicAdd epilogue ----
__global__ __launch_bounds__(256) void xproj_ks(
    const ushort_t* __restrict__ Ahi, const ushort_t* __restrict__ Alo,  // u [8192][1024]
    const ushort_t* __restrict__ Bhi, const ushort_t* __restrict__ Blo,  // xp_w [64][1024]
    float* __restrict__ C)                                                // xdbl [8192][64]
{
    __shared__ __align__(16) char lds[16384];
    char* lAh = lds;            // [64][64B]
    char* lAl = lds + 4096;
    char* lBh = lds + 8192;     // [64][64B]
    char* lBl = lds + 12288;
    int tid = threadIdx.x;
    int lane = tid & 63, wave = tid >> 6;
    int row0 = blockIdx.y * 64;
    int kbeg = blockIdx.x * 256;
    int wr = wave >> 1, wc = wave & 1;
    f4_t acc[2][2];
#pragma unroll
    for (int m=0;m<2;++m)
#pragma unroll
        for (int n=0;n<2;++n)
#pragma unroll
            for (int j=0;j<4;++j) acc[m][n][j] = 0.f;
    int srow = tid >> 2;
    int scol = (tid & 3) * 8;
    int koff = (lane >> 4) * 16;
    int fr = lane & 15;
    for (int k0 = kbeg; k0 < kbeg + 256; k0 += 32) {
        __syncthreads();
        gload_lds16(Ahi + (size_t)(row0 + srow)*D_INNER + k0 + scol, lAh + wave*1024);
        gload_lds16(Alo + (size_t)(row0 + srow)*D_INNER + k0 + scol, lAl + wave*1024);
        gload_lds16(Bhi + (size_t)srow*D_INNER + k0 + scol, lBh + wave*1024);
        gload_lds16(Blo + (size_t)srow*D_INNER + k0 + scol, lBl + wave*1024);
        __syncthreads();
        bf8_t ah[2], al[2], bh[2], bl[2];
#pragma unroll
        for (int m=0;m<2;++m) {
            int r = wr*32 + m*16 + fr;
            ah[m] = *(const bf8_t*)(lAh + r*64 + koff);
            al[m] = *(const bf8_t*)(lAl + r*64 + koff);
        }
#pragma unroll
        for (int n=0;n<2;++n) {
            int c = wc*32 + n*16 + fr;
            bh[n] = *(const bf8_t*)(lBh + c*64 + koff);
            bl[n] = *(const bf8_t*)(lBl + c*64 + koff);
        }
#pragma unroll
        for (int m=0;m<2;++m)
#pragma unroll
            for (int n=0;n<2;++n) {
                acc[m][n] = __builtin_amdgcn_mfma_f32_16x16x32_bf16(ah[m], bh[n], acc[m][n], 0,0,0);
                acc[m][n] = __builtin_amdgcn_mfma_f32_16x16x32_bf16(ah[m], bl[n], acc[m][n], 0,0,0);
                acc[m][n] = __builtin_amdgcn_mfma_f32_16x16x32_bf16(al[m], bh[n], acc[m][n], 0,0,0);
            }
    }
    int fq = (lane >> 4) * 4;
#pragma unroll
    for (int m=0;m<2;++m)
#pragma unroll
        for (int n=0;n<2;++n)
#pragma unroll
            for (int j=0;j<4;++j) {
                int r = row0 + wr*32 + m*16 + fq + j;
                int c = wc*32 + n*16 + fr;
                atomicAdd(&C[(size_t)r*64 + c], acc[m][n][j]);
            }
}

// ---------------- causal depthwise conv (k=4) + SiLU -> bf16 hi/lo ----------------
__global__ __launch_bounds__(256) void conv_silu(const float* __restrict__ xz,
                        const float* __restrict__ cw, const float* __restrict__ cb,
                        ushort_t* __restrict__ uh, ushort_t* __restrict__ ul)
{
    int idx = blockIdx.x * 256 + threadIdx.x;   // (b*SEQ+t)*1024 + d
    int d = idx & (D_INNER-1);
    int t = (idx >> 10) & (SEQ-1);
    float w0 = cw[d*4+0], w1 = cw[d*4+1], w2 = cw[d*4+2], w3 = cw[d*4+3];
    float s = cb[d];
    const float* base = xz + ((size_t)(idx >> 10))*2048 + d;
    if (t >= 3) s = fmaf(w0, base[-3*2048], s);
    if (t >= 2) s = fmaf(w1, base[-2*2048], s);
    if (t >= 1) s = fmaf(w2, base[-1*2048], s);
    s = fmaf(w3, base[0], s);
    float uv = s / (1.f + __expf(-s));
    ushort_t h = f2bf(uv);
    uh[idx] = h;
    ul[idx] = f2bf(uv - bf2f(h));
}

// ---------------- dt_proj (K=32) + bias + softplus, 8 tokens/block (r3-verified) -------
__global__ __launch_bounds__(256) void dt_softplus(const float* __restrict__ xdbl,
                        const float* __restrict__ dtw, const float* __restrict__ dtb,
                        float* __restrict__ delta)
{
    __shared__ float xr[8][32];
    int t0 = blockIdx.x * 8;
    int tid = threadIdx.x;
    {
        int tt = tid >> 5, r = tid & 31;
        xr[tt][r] = xdbl[(size_t)(t0+tt)*64 + r];
    }
    __syncthreads();
#pragma unroll
    for (int jj = 0; jj < 4; ++jj) {
        int j = (jj<<8) + tid;
        const float* w = dtw + (size_t)j*DT_RANK;
        float bj = dtb[j];
        float acc[8];
#pragma unroll
        for (int tt=0;tt<8;++tt) acc[tt]=bj;
#pragma unroll
        for (int r=0;r<DT_RANK;r+=4){
            float4 w4 = *(const float4*)(w+r);
#pragma unroll
            for (int tt=0;tt<8;++tt){
                acc[tt] = fmaf(xr[tt][r+0], w4.x, acc[tt]);
                acc[tt] = fmaf(xr[tt][r+1], w4.y, acc[tt]);
                acc[tt] = fmaf(xr[tt][r+2], w4.z, acc[tt]);
                acc[tt] = fmaf(xr[tt][r+3], w4.w, acc[tt]);
            }
        }
#pragma unroll
        for (int tt=0;tt<8;++tt){
            float s = acc[tt];
            float sp = fmaxf(s,0.f) + log1pf(__expf(-fabsf(s)));
            delta[(size_t)(t0+tt)*D_INNER + j] = sp;
        }
    }
}

// ======== chunked parallel selective scan (r7-verified partial/final) ========
__global__ __launch_bounds__(256) void scan_partial(const float* __restrict__ delta,
                        const ushort_t* __restrict__ uh, const ushort_t* __restrict__ ul,
                        const float* __restrict__ xdbl,
                        const float* __restrict__ A_log,
                        float* __restrict__ P, float* __restrict__ S)
{
    int d = blockIdx.x * 256 + threadIdx.x;
    int c = blockIdx.y;
    int b = blockIdx.z;
    int t0 = c * CL;
    __shared__ float Bsh[CL][16];
    for (int i = threadIdx.x; i < CL*16; i += 256) {
        int tt = i >> 4, n = i & 15;
        Bsh[tt][n] = xdbl[((size_t)(b*SEQ + t0 + tt))*64 + 32 + n];
    }
    __syncthreads();
    float A2[D_STATE];
#pragma unroll
    for (int n = 0; n < D_STATE; ++n)
        A2[n] = -expf(A_log[(size_t)d*D_STATE + n]) * LOG2E;
    bool geo = true;
#pragma unroll
    for (int n = 1; n < D_STATE; ++n)
        geo = geo && (fabsf(A2[n] - (n+1)*A2[0]) <= 1e-4f*fabsf(A2[n]));
    float h[D_STATE];
#pragma unroll
    for (int n = 0; n < D_STATE; ++n) h[n] = 0.f;
    float sdv = 0.f;
    const float* dl = delta + ((size_t)(b*SEQ + t0))*D_INNER + d;
    const ushort_t* uhp = uh + ((size_t)(b*SEQ + t0))*D_INNER + d;
    const ushort_t* ulp = ul + ((size_t)(b*SEQ + t0))*D_INNER + d;
#pragma unroll 4
    for (int t = 0; t < CL; ++t) {
        float dv = dl[(size_t)t*D_INNER];
        float uv = bf2f(uhp[(size_t)t*D_INNER]) + bf2f(ulp[(size_t)t*D_INNER]);
        float du = dv * uv;
        sdv += dv;
        float dA[D_STATE];
        mk_dA(dv, A2, geo, dA);
#pragma unroll
        for (int n = 0; n < D_STATE; ++n)
            h[n] = fmaf(dA[n], h[n], Bsh[t][n] * du);
    }
    size_t base = (((size_t)b*D_INNER + d)*NCHUNK + c)*16;
#pragma unroll
    for (int n = 0; n < D_STATE; ++n) P[base+n] = exp2f(A2[n]*sdv);
#pragma unroll
    for (int n = 0; n < D_STATE; n += 4)
        *(float4*)&S[base+n] = make_float4(h[n],h[n+1],h[n+2],h[n+3]);
}

// one thread per (b,d,n): coalesced, 65536-way parallel. S[c] <- h_start(c) in-place.
__global__ __launch_bounds__(256) void scan_boundary(const float* __restrict__ P,
                        float* __restrict__ S)
{
    int gid = blockIdx.x * 256 + threadIdx.x;   // 0..65535 = (b*1024+d)*16 + n
    int n  = gid & 15;
    size_t base = ((size_t)(gid >> 4))*NCHUNK*16 + n;
    float h = 0.f;
    for (int c = 0; c < NCHUNK; ++c) {
        size_t o = base + (size_t)c*16;
        float p = P[o];
        float s = S[o];
        S[o] = h;
        h = fmaf(p, h, s);
    }
}

__global__ __launch_bounds__(256) void scan_final(const float* __restrict__ delta,
                        const ushort_t* __restrict__ uh, const ushort_t* __restrict__ ul,
                        float* __restrict__ xz,
                        const float* __restrict__ xdbl,
                        const float* __restrict__ A_log,
                        const float* __restrict__ Dp,
                        const float* __restrict__ Hs)
{
    int d = blockIdx.x * 256 + threadIdx.x;
    int c = blockIdx.y;
    int b = blockIdx.z;
    int t0 = c * CL;
    __shared__ float Bsh[CL][16];
    __shared__ float Csh[CL][16];
    for (int i = threadIdx.x; i < CL*16; i += 256) {
        int tt = i >> 4, n = i & 15;
        size_t xo = ((size_t)(b*SEQ + t0 + tt))*64;
        Bsh[tt][n] = xdbl[xo + 32 + n];
        Csh[tt][n] = xdbl[xo + 48 + n];
    }
    __syncthreads();
    float A2[D_STATE];
#pragma unroll
    for (int n = 0; n < D_STATE; ++n)
        A2[n] = -expf(A_log[(size_t)d*D_STATE + n]) * LOG2E;
    bool geo = true;
#pragma unroll
    for (int n = 1; n < D_STATE; ++n)
        geo = geo && (fabsf(A2[n] - (n+1)*A2[0]) <= 1e-4f*fabsf(A2[n]));
    float Dd = Dp[d];
    float h[D_STATE];
    size_t hbase = (((size_t)b*D_INNER + d)*NCHUNK + c)*16;
#pragma unroll
    for (int n = 0; n < D_STATE; n += 4) {
        float4 h4 = *(const float4*)&Hs[hbase+n];
        h[n]=h4.x; h[n+1]=h4.y; h[n+2]=h4.z; h[n+3]=h4.w;
    }
    const float* dl = delta + ((size_t)(b*SEQ + t0))*D_INNER + d;
    const ushort_t* uhp = uh + ((size_t)(b*SEQ + t0))*D_INNER + d;
    const ushort_t* ulp = ul + ((size_t)(b*SEQ + t0))*D_INNER + d;
    const float* zl = xz + ((size_t)(b*SEQ + t0))*2048 + 1024 + d;
    ushort_t* yrow = (ushort_t*)(xz + ((size_t)(b*SEQ + t0))*2048);
#pragma unroll 4
    for (int t = 0; t < CL; ++t) {
        float dv = dl[(size_t)t*D_INNER];
        float uv = bf2f(uhp[(size_t)t*D_INNER]) + bf2f(ulp[(size_t)t*D_INNER]);
        float zv = zl[(size_t)t*2048];
        float du = dv * uv;
        float dA[D_STATE];
        mk_dA(dv, A2, geo, dA);
        float y = 0.f;
#pragma unroll
        for (int n = 0; n < D_STATE; ++n) {
            h[n] = fmaf(dA[n], h[n], Bsh[t][n] * du);
            y = fmaf(h[n], Csh[t][n], y);
        }
        y = fmaf(uv, Dd, y);
        float sig = 1.f / (1.f + __expf(-zv));
        float yg = y * (zv * sig);
        ushort_t yh = f2bf(yg);
        yrow[(size_t)t*4096 + d] = yh;
        yrow[(size_t)t*4096 + 1024 + d] = f2bf(yg - bf2f(yh));
    }
}

extern "C" void kernel_launch(void* const* d_in, const int* in_sizes, int n_in,
                              void* d_out, int out_size, void* d_ws, size_t ws_size,
                              hipStream_t stream) {
    const float* x_in   = (const float*)d_in[0];
    const float* norm_w = (const float*)d_in[1];
    const float* norm_b = (const float*)d_in[2];
    const float* in_w   = (const float*)d_in[3];
    const float* conv_w = (const float*)d_in[4];
    const float* conv_b = (const float*)d_in[5];
    const float* xp_w   = (const float*)d_in[6];
    const float* dt_w   = (const float*)d_in[7];
    const float* dt_b   = (const float*)d_in[8];
    const float* A_log  = (const float*)d_in[9];
    const float* Dp     = (const float*)d_in[10];
    const float* out_w  = (const float*)d_in[11];
    float* out = (float*)d_out;

    // workspace (~170 MB, r2-proven size)
    float* ws   = (float*)d_ws;
    float* xz   = ws;                           // 64MB f32 (xi|z); y bf16 hi/lo aliased later
    ushort_t* uhb = (ushort_t*)(xz + (size_t)NTOK*2048);   // 16MB
    ushort_t* ulb = uhb + (size_t)NTOK*D_INNER;            // 16MB
    float* xdbl = (float*)(ulb + (size_t)NTOK*D_INNER);    // 2MB
    float* dlt  = xdbl + (size_t)NTOK*64;                  // 32MB (head aliases xnh/xnl)
    float* Pb   = dlt  + (size_t)NTOK*D_INNER;             // 16.8MB
    float* Sb   = Pb   + (size_t)BATCH*D_INNER*NCHUNK*16;  // 16.8MB (becomes Hs in-place)
    ushort_t* wih = (ushort_t*)(Sb + (size_t)BATCH*D_INNER*NCHUNK*16);
    ushort_t* wil = wih + (size_t)2*D_INNER*D_MODEL;
    ushort_t* woh = wil + (size_t)2*D_INNER*D_MODEL;
    ushort_t* wol = woh + (size_t)D_MODEL*D_INNER;
    ushort_t* xph = wol + (size_t)D_MODEL*D_INNER;
    ushort_t* xpl = xph + (size_t)64*D_INNER;
    ushort_t* xnh = (ushort_t*)dlt;             // alias: consumed before dlt written
    ushort_t* xnl = xnh + (size_t)NTOK*D_MODEL;

    for (int l = 0; l < N_LAYERS; ++l) {
        const float* xcur = (l == 0) ? x_in : out;
        prep<<<3648, 256, 0, stream>>>(
            xcur, norm_w + l*D_MODEL, norm_b + l*D_MODEL, xnh, xnl,
            in_w + (size_t)l*2*D_INNER*D_MODEL, wih, wil,
            out_w + (size_t)l*D_MODEL*D_INNER, woh, wol,
            xp_w + (size_t)l*64*D_INNER, xph, xpl);
        // xz = xn @ in_w^T   (M=8192, N=2048, K=512)
        gemm_bf16s<128,128,false><<<dim3(2048/128, NTOK/128), 256, 0, stream>>>(
            xnh, xnl, D_MODEL, wih, wil, D_MODEL, xz, 2048, nullptr, D_MODEL);
        // conv + silu -> u bf16 hi/lo
        conv_silu<<<(NTOK*D_INNER)/256, 256, 0, stream>>>(
            xz, conv_w + (size_t)l*D_INNER*D_CONV, conv_b + (size_t)l*D_INNER, uhb, ulb);
        // xdbl = u @ xp_w^T  (M=8192, N=64, K=1024), K-split x4 + atomicAdd
        hipMemsetAsync(xdbl, 0, (size_t)NTOK*64*sizeof(float), stream);
        xproj_ks<<<dim3(4, NTOK/64), 256, 0, stream>>>(uhb, ulb, xph, xpl, xdbl);
        // delta = softplus(dt @ dtw^T + b)
        dt_softplus<<<NTOK/8, 256, 0, stream>>>(
            xdbl, dt_w + (size_t)l*D_INNER*DT_RANK, dt_b + (size_t)l*D_INNER, dlt);
        // chunked scan
        scan_partial<<<dim3(D_INNER/256, NCHUNK, BATCH), 256, 0, stream>>>(
            dlt, uhb, ulb, xdbl, A_log + (size_t)l*D_INNER*D_STATE, Pb, Sb);
        scan_boundary<<<256, 256, 0, stream>>>(Pb, Sb);
        scan_final<<<dim3(D_INNER/256, NCHUNK, BATCH), 256, 0, stream>>>(
            dlt, uhb, ulb, xz, xdbl, A_log + (size_t)l*D_INNER*D_STATE, Dp + (size_t)l*D_INNER, Sb);
        // out = y @ out_w^T + xcur  (M=8192, N=512, K=1024); y bf16 hi/lo packed in xz rows
        gemm_bf16s<64,128,true><<<dim3(D_MODEL/128, NTOK/64), 256, 0, stream>>>(
            (const ushort_t*)xz, (const ushort_t*)xz + 1024, 4096,
            woh, wol, D_INNER, out, D_MODEL, xcur, D_INNER);
    }
}

// Round 10
// 1231.055 us; speedup vs baseline: 1.6581x; 1.0186x over previous
//
#include <hip/hip_runtime.h>
#include <math.h>

#define D_MODEL 512
#define N_LAYERS 4
#define D_STATE 16
#define D_CONV 4
#define D_INNER 1024
#define DT_RANK 32
#define BATCH 4
#define SEQ 2048
#define NTOK (BATCH*SEQ)   // 8192
#define NCHUNK 64
#define CL (SEQ/NCHUNK)    // 32
#define LOG2E 1.44269504f

typedef unsigned short ushort_t;
typedef __attribute__((ext_vector_type(8))) short bf8_t;
typedef __attribute__((ext_vector_type(4))) float f4_t;

__device__ __forceinline__ ushort_t f2bf(float f) {
    unsigned u = __float_as_uint(f);
    u += 0x7fffu + ((u >> 16) & 1u);
    return (ushort_t)(u >> 16);
}
__device__ __forceinline__ float bf2f(ushort_t h) {
    return __uint_as_float(((unsigned)h) << 16);
}
__device__ __forceinline__ void gload_lds16(const void* g, void* l) {
    auto* gp = (const __attribute__((address_space(1))) unsigned int*)(unsigned long long)(g);
    auto* lp = (__attribute__((address_space(3))) unsigned int*)(unsigned int)(unsigned long long)(l);
    __builtin_amdgcn_global_load_lds(gp, lp, 16, 0, 0);
}
__device__ __forceinline__ void split4(const float* __restrict__ src,
        ushort_t* __restrict__ dh, ushort_t* __restrict__ dl, int rel)
{
    float4 v = ((const float4*)src)[rel];
    ushort_t h0=f2bf(v.x), h1=f2bf(v.y), h2=f2bf(v.z), h3=f2bf(v.w);
    ((ushort4*)dh)[rel] = make_ushort4(h0,h1,h2,h3);
    ((ushort4*)dl)[rel] = make_ushort4(f2bf(v.x-bf2f(h0)), f2bf(v.y-bf2f(h1)),
                                       f2bf(v.z-bf2f(h2)), f2bf(v.w-bf2f(h3)));
}
// geometric-A fast path: dA[n] = r^(n+1), r = exp2(dv*A2[0]); else 16 exps.
__device__ __forceinline__ void mk_dA(float dv, const float* A2, bool geo, float* dA)
{
    if (geo) {
        float r1 = exp2f(dv * A2[0]);
        float r2 = r1*r1, r4 = r2*r2, r8 = r4*r4;
        dA[0]=r1;  dA[1]=r2;     dA[2]=r2*r1;    dA[3]=r4;
        dA[4]=r4*r1; dA[5]=r4*r2; dA[6]=r4*r2*r1; dA[7]=r8;
        dA[8]=r8*r1; dA[9]=r8*r2; dA[10]=r8*r2*r1; dA[11]=r8*r4;
        dA[12]=r8*r4*r1; dA[13]=r8*r4*r2; dA[14]=r8*r4*r2*r1; dA[15]=r8*r8;
    } else {
#pragma unroll
        for (int n = 0; n < 16; ++n) dA[n] = exp2f(dv * A2[n]);
    }
}

// ===== prep: LN (2048 blks) | split in_w (1024) | out_w (512) | xp_w (64) =====
__global__ __launch_bounds__(256) void prep(
    const float* __restrict__ x, const float* __restrict__ nw, const float* __restrict__ nb,
    ushort_t* __restrict__ xnh, ushort_t* __restrict__ xnl,
    const float* __restrict__ inw, ushort_t* __restrict__ wih, ushort_t* __restrict__ wil,
    const float* __restrict__ outw, ushort_t* __restrict__ woh, ushort_t* __restrict__ wol,
    const float* __restrict__ xpw, ushort_t* __restrict__ xph, ushort_t* __restrict__ xpl)
{
    int bid = blockIdx.x, tid = threadIdx.x;
    if (bid < 2048) {
        int wave = tid >> 6, lane = tid & 63;
        int row = bid * 4 + wave;
        const float* xr = x + (size_t)row * D_MODEL;
        float v[8];
        float s = 0.f;
#pragma unroll
        for (int i = 0; i < 8; ++i) { v[i] = xr[lane + i*64]; s += v[i]; }
#pragma unroll
        for (int off = 32; off > 0; off >>= 1) s += __shfl_xor(s, off, 64);
        float mu = s * (1.f/512.f);
        float q = 0.f;
#pragma unroll
        for (int i = 0; i < 8; ++i) { float d = v[i]-mu; q += d*d; }
#pragma unroll
        for (int off = 32; off > 0; off >>= 1) q += __shfl_xor(q, off, 64);
        float rstd = rsqrtf(q * (1.f/512.f) + 1e-5f);
#pragma unroll
        for (int i = 0; i < 8; ++i) {
            int e = lane + i*64;
            float vv = (v[i]-mu)*rstd*nw[e] + nb[e];
            ushort_t h = f2bf(vv);
            xnh[(size_t)row*D_MODEL + e] = h;
            xnl[(size_t)row*D_MODEL + e] = f2bf(vv - bf2f(h));
        }
    } else if (bid < 3072) {
        split4(inw, wih, wil, (bid-2048)*256 + tid);          // 262144 f4
    } else if (bid < 3584) {
        split4(outw, woh, wol, (bid-3072)*256 + tid);         // 131072 f4
    } else {
        split4(xpw, xph, xpl, (bid-3584)*256 + tid);          // 16384 f4
    }
}

// ------- bf16 split-MFMA NT GEMM (r3-verified) -------
template<int BM, int BN, bool RES>
__global__ __launch_bounds__(256) void gemm_bf16s(
    const ushort_t* __restrict__ Ahi, const ushort_t* __restrict__ Alo, int lda,
    const ushort_t* __restrict__ Bhi, const ushort_t* __restrict__ Blo, int ldb,
    float* __restrict__ C, int ldc, const float* __restrict__ resid, int K)
{
    constexpr int MR = BM/32, NR = BN/32;
    __shared__ __align__(16) char lds[(2*BM + 2*BN)*64];
    char* lAh = lds;
    char* lAl = lds + BM*64;
    char* lBh = lds + 2*BM*64;
    char* lBl = lds + 2*BM*64 + BN*64;
    int tid = threadIdx.x;
    int lane = tid & 63, wave = tid >> 6;
    int row0 = blockIdx.y * BM, col0 = blockIdx.x * BN;
    int wr = wave >> 1, wc = wave & 1;
    f4_t acc[MR][NR];
#pragma unroll
    for (int m=0;m<MR;++m)
#pragma unroll
        for (int n=0;n<NR;++n)
#pragma unroll
            for (int j=0;j<4;++j) acc[m][n][j] = 0.f;

    int srow = tid >> 2;
    int scol = (tid & 3) * 8;
    int koff = (lane >> 4) * 16;
    int fr = lane & 15;

    for (int k0 = 0; k0 < K; k0 += 32) {
        __syncthreads();
        gload_lds16(Ahi + (size_t)(row0 + srow)*lda + k0 + scol, lAh + wave*1024);
        gload_lds16(Alo + (size_t)(row0 + srow)*lda + k0 + scol, lAl + wave*1024);
        if (BM == 128) {
            gload_lds16(Ahi + (size_t)(row0 + 64 + srow)*lda + k0 + scol, lAh + 4096 + wave*1024);
            gload_lds16(Alo + (size_t)(row0 + 64 + srow)*lda + k0 + scol, lAl + 4096 + wave*1024);
        }
        gload_lds16(Bhi + (size_t)(col0 + srow)*ldb + k0 + scol, lBh + wave*1024);
        gload_lds16(Blo + (size_t)(col0 + srow)*ldb + k0 + scol, lBl + wave*1024);
        if (BN == 128) {
            gload_lds16(Bhi + (size_t)(col0 + 64 + srow)*ldb + k0 + scol, lBh + 4096 + wave*1024);
            gload_lds16(Blo + (size_t)(col0 + 64 + srow)*ldb + k0 + scol, lBl + 4096 + wave*1024);
        }
        __syncthreads();
        bf8_t ah[MR], al[MR], bh[NR], bl[NR];
#pragma unroll
        for (int m=0;m<MR;++m) {
            int r = wr*(BM/2) + m*16 + fr;
            ah[m] = *(const bf8_t*)(lAh + r*64 + koff);
            al[m] = *(const bf8_t*)(lAl + r*64 + koff);
        }
#pragma unroll
        for (int n=0;n<NR;++n) {
            int c = wc*(BN/2) + n*16 + fr;
            bh[n] = *(const bf8_t*)(lBh + c*64 + koff);
            bl[n] = *(const bf8_t*)(lBl + c*64 + koff);
        }
#pragma unroll
        for (int m=0;m<MR;++m)
#pragma unroll
            for (int n=0;n<NR;++n) {
                acc[m][n] = __builtin_amdgcn_mfma_f32_16x16x32_bf16(ah[m], bh[n], acc[m][n], 0,0,0);
                acc[m][n] = __builtin_amdgcn_mfma_f32_16x16x32_bf16(ah[m], bl[n], acc[m][n], 0,0,0);
                acc[m][n] = __builtin_amdgcn_mfma_f32_16x16x32_bf16(al[m], bh[n], acc[m][n], 0,0,0);
            }
    }
    int fq = (lane >> 4) * 4;
#pragma unroll
    for (int m=0;m<MR;++m)
#pragma unroll
        for (int n=0;n<NR;++n)
#pragma unroll
            for (int j=0;j<4;++j) {
                int r = row0 + wr*(BM/2) + m*16 + fq + j;
                int c = col0 + wc*(BN/2) + n*16 + fr;
                float v = acc[m][n][j];
                if (RES) v += resid[(size_t)r*ldc + c];
                C[(size_t)r*ldc + c] = v;
            }
}

// ---- x_proj split-bf16 MFMA, BM=64 + K-split x4, atomicAdd epilogue ----
__global__ __launch_bounds__(256) void xproj_ks(
    const ushort_t* __restrict__ Ahi, const ushort_t* __restrict__ Alo,  // u [8192][1024]
    const ushort_t* __restrict__ Bhi, const ushort_t* __restrict__ Blo,  // xp_w [64][1024]
    float* __restrict__ C)                                                // xdbl [8192][64]
{
    __shared__ __align__(16) char lds[16384];
    char* lAh = lds;            // [64][64B]
    char* lAl = lds + 4096;
    char* lBh = lds + 8192;     // [64][64B]
    char* lBl = lds + 12288;
    int tid = threadIdx.x;
    int lane = tid & 63, wave = tid >> 6;
    int row0 = blockIdx.y * 64;
    int kbeg = blockIdx.x * 256;
    int wr = wave >> 1, wc = wave & 1;
    f4_t acc[2][2];
#pragma unroll
    for (int m=0;m<2;++m)
#pragma unroll
        for (int n=0;n<2;++n)
#pragma unroll
            for (int j=0;j<4;++j) acc[m][n][j] = 0.f;
    int srow = tid >> 2;
    int scol = (tid & 3) * 8;
    int koff = (lane >> 4) * 16;
    int fr = lane & 15;
    for (int k0 = kbeg; k0 < kbeg + 256; k0 += 32) {
        __syncthreads();
        gload_lds16(Ahi + (size_t)(row0 + srow)*D_INNER + k0 + scol, lAh + wave*1024);
        gload_lds16(Alo + (size_t)(row0 + srow)*D_INNER + k0 + scol, lAl + wave*1024);
        gload_lds16(Bhi + (size_t)srow*D_INNER + k0 + scol, lBh + wave*1024);
        gload_lds16(Blo + (size_t)srow*D_INNER + k0 + scol, lBl + wave*1024);
        __syncthreads();
        bf8_t ah[2], al[2], bh[2], bl[2];
#pragma unroll
        for (int m=0;m<2;++m) {
            int r = wr*32 + m*16 + fr;
            ah[m] = *(const bf8_t*)(lAh + r*64 + koff);
            al[m] = *(const bf8_t*)(lAl + r*64 + koff);
        }
#pragma unroll
        for (int n=0;n<2;++n) {
            int c = wc*32 + n*16 + fr;
            bh[n] = *(const bf8_t*)(lBh + c*64 + koff);
            bl[n] = *(const bf8_t*)(lBl + c*64 + koff);
        }
#pragma unroll
        for (int m=0;m<2;++m)
#pragma unroll
            for (int n=0;n<2;++n) {
                acc[m][n] = __builtin_amdgcn_mfma_f32_16x16x32_bf16(ah[m], bh[n], acc[m][n], 0,0,0);
                acc[m][n] = __builtin_amdgcn_mfma_f32_16x16x32_bf16(ah[m], bl[n], acc[m][n], 0,0,0);
                acc[m][n] = __builtin_amdgcn_mfma_f32_16x16x32_bf16(al[m], bh[n], acc[m][n], 0,0,0);
            }
    }
    int fq = (lane >> 4) * 4;
#pragma unroll
    for (int m=0;m<2;++m)
#pragma unroll
        for (int n=0;n<2;++n)
#pragma unroll
            for (int j=0;j<4;++j) {
                int r = row0 + wr*32 + m*16 + fq + j;
                int c = wc*32 + n*16 + fr;
                atomicAdd(&C[(size_t)r*64 + c], acc[m][n][j]);
            }
}

// ---------------- causal depthwise conv (k=4) + SiLU -> bf16 hi/lo ----------------
__global__ __launch_bounds__(256) void conv_silu(const float* __restrict__ xz,
                        const float* __restrict__ cw, const float* __restrict__ cb,
                        ushort_t* __restrict__ uh, ushort_t* __restrict__ ul)
{
    int idx = blockIdx.x * 256 + threadIdx.x;   // (b*SEQ+t)*1024 + d
    int d = idx & (D_INNER-1);
    int t = (idx >> 10) & (SEQ-1);
    float w0 = cw[d*4+0], w1 = cw[d*4+1], w2 = cw[d*4+2], w3 = cw[d*4+3];
    float s = cb[d];
    const float* base = xz + ((size_t)(idx >> 10))*2048 + d;
    if (t >= 3) s = fmaf(w0, base[-3*2048], s);
    if (t >= 2) s = fmaf(w1, base[-2*2048], s);
    if (t >= 1) s = fmaf(w2, base[-1*2048], s);
    s = fmaf(w3, base[0], s);
    float uv = s / (1.f + __expf(-s));
    ushort_t h = f2bf(uv);
    uh[idx] = h;
    ul[idx] = f2bf(uv - bf2f(h));
}

// ======== chunked parallel selective scan ========
// scan_partial now ALSO computes delta = softplus(dt@dtw^T + b) (dt_softplus folded in)
__global__ __launch_bounds__(256) void scan_partial(
                        const ushort_t* __restrict__ uh, const ushort_t* __restrict__ ul,
                        const float* __restrict__ xdbl,
                        const float* __restrict__ dtw, const float* __restrict__ dtb,
                        const float* __restrict__ A_log,
                        float* __restrict__ delta,
                        float* __restrict__ P, float* __restrict__ S)
{
    int d = blockIdx.x * 256 + threadIdx.x;
    int c = blockIdx.y;
    int b = blockIdx.z;
    int t0 = c * CL;
    __shared__ float Bsh[CL][16];
    __shared__ float dtsh[CL][32];
    for (int i = threadIdx.x; i < CL*16; i += 256) {
        int tt = i >> 4, n = i & 15;
        Bsh[tt][n] = xdbl[((size_t)(b*SEQ + t0 + tt))*64 + 32 + n];
    }
    for (int i = threadIdx.x; i < CL*32; i += 256) {
        int tt = i >> 5, r = i & 31;
        dtsh[tt][r] = xdbl[((size_t)(b*SEQ + t0 + tt))*64 + r];
    }
    __syncthreads();
    float wreg[DT_RANK];
#pragma unroll
    for (int r = 0; r < DT_RANK; ++r) wreg[r] = dtw[(size_t)d*DT_RANK + r];
    float bj = dtb[d];
    float A2[D_STATE];
#pragma unroll
    for (int n = 0; n < D_STATE; ++n)
        A2[n] = -expf(A_log[(size_t)d*D_STATE + n]) * LOG2E;
    bool geo = true;
#pragma unroll
    for (int n = 1; n < D_STATE; ++n)
        geo = geo && (fabsf(A2[n] - (n+1)*A2[0]) <= 1e-4f*fabsf(A2[n]));
    float h[D_STATE];
#pragma unroll
    for (int n = 0; n < D_STATE; ++n) h[n] = 0.f;
    float sdv = 0.f;
    const ushort_t* uhp = uh + ((size_t)(b*SEQ + t0))*D_INNER + d;
    const ushort_t* ulp = ul + ((size_t)(b*SEQ + t0))*D_INNER + d;
    float* dlp = delta + ((size_t)(b*SEQ + t0))*D_INNER + d;
#pragma unroll 2
    for (int t = 0; t < CL; ++t) {
        float sraw = bj;
#pragma unroll
        for (int r = 0; r < DT_RANK; ++r) sraw = fmaf(dtsh[t][r], wreg[r], sraw);
        float dv = fmaxf(sraw,0.f) + log1pf(__expf(-fabsf(sraw)));
        dlp[(size_t)t*D_INNER] = dv;
        float uv = bf2f(uhp[(size_t)t*D_INNER]) + bf2f(ulp[(size_t)t*D_INNER]);
        float du = dv * uv;
        sdv += dv;
        float dA[D_STATE];
        mk_dA(dv, A2, geo, dA);
#pragma unroll
        for (int n = 0; n < D_STATE; ++n)
            h[n] = fmaf(dA[n], h[n], Bsh[t][n] * du);
    }
    size_t base = (((size_t)b*D_INNER + d)*NCHUNK + c)*16;
#pragma unroll
    for (int n = 0; n < D_STATE; ++n) P[base+n] = exp2f(A2[n]*sdv);
#pragma unroll
    for (int n = 0; n < D_STATE; n += 4)
        *(float4*)&S[base+n] = make_float4(h[n],h[n+1],h[n+2],h[n+3]);
}

// one thread per (b,d,n): coalesced, 65536-way parallel. S[c] <- h_start(c) in-place.
__global__ __launch_bounds__(256) void scan_boundary(const float* __restrict__ P,
                        float* __restrict__ S)
{
    int gid = blockIdx.x * 256 + threadIdx.x;   // 0..65535 = (b*1024+d)*16 + n
    int n  = gid & 15;
    size_t base = ((size_t)(gid >> 4))*NCHUNK*16 + n;
    float h = 0.f;
    for (int c = 0; c < NCHUNK; ++c) {
        size_t o = base + (size_t)c*16;
        float p = P[o];
        float s = S[o];
        S[o] = h;
        h = fmaf(p, h, s);
    }
}

__global__ __launch_bounds__(256) void scan_final(const float* __restrict__ delta,
                        const ushort_t* __restrict__ uh, const ushort_t* __restrict__ ul,
                        float* __restrict__ xz,
                        const float* __restrict__ xdbl,
                        const float* __restrict__ A_log,
                        const float* __restrict__ Dp,
                        const float* __restrict__ Hs)
{
    int d = blockIdx.x * 256 + threadIdx.x;
    int c = blockIdx.y;
    int b = blockIdx.z;
    int t0 = c * CL;
    __shared__ float Bsh[CL][16];
    __shared__ float Csh[CL][16];
    for (int i = threadIdx.x; i < CL*16; i += 256) {
        int tt = i >> 4, n = i & 15;
        size_t xo = ((size_t)(b*SEQ + t0 + tt))*64;
        Bsh[tt][n] = xdbl[xo + 32 + n];
        Csh[tt][n] = xdbl[xo + 48 + n];
    }
    __syncthreads();
    float A2[D_STATE];
#pragma unroll
    for (int n = 0; n < D_STATE; ++n)
        A2[n] = -expf(A_log[(size_t)d*D_STATE + n]) * LOG2E;
    bool geo = true;
#pragma unroll
    for (int n = 1; n < D_STATE; ++n)
        geo = geo && (fabsf(A2[n] - (n+1)*A2[0]) <= 1e-4f*fabsf(A2[n]));
    float Dd = Dp[d];
    float h[D_STATE];
    size_t hbase = (((size_t)b*D_INNER + d)*NCHUNK + c)*16;
#pragma unroll
    for (int n = 0; n < D_STATE; n += 4) {
        float4 h4 = *(const float4*)&Hs[hbase+n];
        h[n]=h4.x; h[n+1]=h4.y; h[n+2]=h4.z; h[n+3]=h4.w;
    }
    const float* dl = delta + ((size_t)(b*SEQ + t0))*D_INNER + d;
    const ushort_t* uhp = uh + ((size_t)(b*SEQ + t0))*D_INNER + d;
    const ushort_t* ulp = ul + ((size_t)(b*SEQ + t0))*D_INNER + d;
    const float* zl = xz + ((size_t)(b*SEQ + t0))*2048 + 1024 + d;
    ushort_t* yrow = (ushort_t*)(xz + ((size_t)(b*SEQ + t0))*2048);
#pragma unroll 4
    for (int t = 0; t < CL; ++t) {
        float dv = dl[(size_t)t*D_INNER];
        float uv = bf2f(uhp[(size_t)t*D_INNER]) + bf2f(ulp[(size_t)t*D_INNER]);
        float zv = zl[(size_t)t*2048];
        float du = dv * uv;
        float dA[D_STATE];
        mk_dA(dv, A2, geo, dA);
        float y = 0.f;
#pragma unroll
        for (int n = 0; n < D_STATE; ++n) {
            h[n] = fmaf(dA[n], h[n], Bsh[t][n] * du);
            y = fmaf(h[n], Csh[t][n], y);
        }
        y = fmaf(uv, Dd, y);
        float sig = 1.f / (1.f + __expf(-zv));
        float yg = y * (zv * sig);
        ushort_t yh = f2bf(yg);
        yrow[(size_t)t*4096 + d] = yh;
        yrow[(size_t)t*4096 + 1024 + d] = f2bf(yg - bf2f(yh));
    }
}

extern "C" void kernel_launch(void* const* d_in, const int* in_sizes, int n_in,
                              void* d_out, int out_size, void* d_ws, size_t ws_size,
                              hipStream_t stream) {
    const float* x_in   = (const float*)d_in[0];
    const float* norm_w = (const float*)d_in[1];
    const float* norm_b = (const float*)d_in[2];
    const float* in_w   = (const float*)d_in[3];
    const float* conv_w = (const float*)d_in[4];
    const float* conv_b = (const float*)d_in[5];
    const float* xp_w   = (const float*)d_in[6];
    const float* dt_w   = (const float*)d_in[7];
    const float* dt_b   = (const float*)d_in[8];
    const float* A_log  = (const float*)d_in[9];
    const float* Dp     = (const float*)d_in[10];
    const float* out_w  = (const float*)d_in[11];
    float* out = (float*)d_out;

    // workspace (~170 MB, r2-proven size)
    float* ws   = (float*)d_ws;
    float* xz   = ws;                           // 64MB f32 (xi|z); y bf16 hi/lo aliased later
    ushort_t* uhb = (ushort_t*)(xz + (size_t)NTOK*2048);   // 16MB
    ushort_t* ulb = uhb + (size_t)NTOK*D_INNER;            // 16MB
    float* xdbl = (float*)(ulb + (size_t)NTOK*D_INNER);    // 2MB
    float* dlt  = xdbl + (size_t)NTOK*64;                  // 32MB (head aliases xnh/xnl)
    float* Pb   = dlt  + (size_t)NTOK*D_INNER;             // 16.8MB
    float* Sb   = Pb   + (size_t)BATCH*D_INNER*NCHUNK*16;  // 16.8MB (becomes Hs in-place)
    ushort_t* wih = (ushort_t*)(Sb + (size_t)BATCH*D_INNER*NCHUNK*16);
    ushort_t* wil = wih + (size_t)2*D_INNER*D_MODEL;
    ushort_t* woh = wil + (size_t)2*D_INNER*D_MODEL;
    ushort_t* wol = woh + (size_t)D_MODEL*D_INNER;
    ushort_t* xph = wol + (size_t)D_MODEL*D_INNER;
    ushort_t* xpl = xph + (size_t)64*D_INNER;
    ushort_t* xnh = (ushort_t*)dlt;             // alias: consumed before dlt written
    ushort_t* xnl = xnh + (size_t)NTOK*D_MODEL;

    for (int l = 0; l < N_LAYERS; ++l) {
        const float* xcur = (l == 0) ? x_in : out;
        prep<<<3648, 256, 0, stream>>>(
            xcur, norm_w + l*D_MODEL, norm_b + l*D_MODEL, xnh, xnl,
            in_w + (size_t)l*2*D_INNER*D_MODEL, wih, wil,
            out_w + (size_t)l*D_MODEL*D_INNER, woh, wol,
            xp_w + (size_t)l*64*D_INNER, xph, xpl);
        // xz = xn @ in_w^T   (M=8192, N=2048, K=512)
        gemm_bf16s<128,128,false><<<dim3(2048/128, NTOK/128), 256, 0, stream>>>(
            xnh, xnl, D_MODEL, wih, wil, D_MODEL, xz, 2048, nullptr, D_MODEL);
        // conv + silu -> u bf16 hi/lo
        conv_silu<<<(NTOK*D_INNER)/256, 256, 0, stream>>>(
            xz, conv_w + (size_t)l*D_INNER*D_CONV, conv_b + (size_t)l*D_INNER, uhb, ulb);
        // xdbl = u @ xp_w^T  (M=8192, N=64, K=1024), K-split x4 + atomicAdd
        hipMemsetAsync(xdbl, 0, (size_t)NTOK*64*sizeof(float), stream);
        xproj_ks<<<dim3(4, NTOK/64), 256, 0, stream>>>(uhb, ulb, xph, xpl, xdbl);
        // chunked scan (partial also computes delta = softplus(dt@dtw^T+b))
        scan_partial<<<dim3(D_INNER/256, NCHUNK, BATCH), 256, 0, stream>>>(
            uhb, ulb, xdbl, dt_w + (size_t)l*D_INNER*DT_RANK, dt_b + (size_t)l*D_INNER,
            A_log + (size_t)l*D_INNER*D_STATE, dlt, Pb, Sb);
        scan_boundary<<<256, 256, 0, stream>>>(Pb, Sb);
        scan_final<<<dim3(D_INNER/256, NCHUNK, BATCH), 256, 0, stream>>>(
            dlt, uhb, ulb, xz, xdbl, A_log + (size_t)l*D_INNER*D_STATE, Dp + (size_t)l*D_INNER, Sb);
        // out = y @ out_w^T + xcur  (M=8192, N=512, K=1024); y bf16 hi/lo packed in xz rows
        gemm_bf16s<128,128,true><<<dim3(D_MODEL/128, NTOK/128), 256, 0, stream>>>(
            (const ushort_t*)xz, (const ushort_t*)xz + 1024, 4096,
            woh, wol, D_INNER, out, D_MODEL, xcur, D_INNER);
    }
}